// Round 5
// baseline (1961.824 us; speedup 1.0000x reference)
//
#include <hip/hip_runtime.h>
#include <hip/hip_bf16.h>

#define NCRYST 256
#define AATOMS 64
#define KNBR   20
#define HID    128
#define LAT    256
#define NRBF   128
#define NBLK   3
#define NATOMS (NCRYST * AATOMS)   // 16384
#define NEDGE  (NATOMS * KNBR)     // 327680
#define NPART  4                   // agg partial slices per crystal
#define PI_F   3.14159265358979323846f
#define CUT_F  6.0f

typedef short short8 __attribute__((ext_vector_type(8)));   // 8 bf16 (4 VGPRs)
typedef float f32x4  __attribute__((ext_vector_type(4)));   // MFMA C/D

__device__ __forceinline__ float bf2f(__hip_bfloat16 x) { return __bfloat162float(x); }
__device__ __forceinline__ __hip_bfloat16 f2bf(float x) { return __float2bfloat16(x); }

// ---------------------------------------------------------------- cart coords
__global__ void k_cart(const float* __restrict__ frac, const float* __restrict__ lengths,
                       const float* __restrict__ angles, float* __restrict__ cart) {
  int atom = blockIdx.x * blockDim.x + threadIdx.x;
  if (atom >= NATOMS) return;
  int c = atom >> 6;
  float al = angles[c*3+0] * (PI_F/180.f);
  float be = angles[c*3+1] * (PI_F/180.f);
  float ga = angles[c*3+2] * (PI_F/180.f);
  float ca = cosf(al), cb = cosf(be), cg = cosf(ga), sg = sinf(ga);
  float a = lengths[c*3+0], b = lengths[c*3+1], cl = lengths[c*3+2];
  float cx = cl * cb;
  float cy = cl * (ca - cb*cg) / sg;
  float cz = sqrtf(fmaxf(cl*cl - cx*cx - cy*cy, 1e-8f));
  float f0 = frac[atom*3+0], f1 = frac[atom*3+1], f2 = frac[atom*3+2];
  cart[atom*3+0] = f0*a + f1*(b*cg) + f2*cx;
  cart[atom*3+1] = f1*(b*sg) + f2*cy;
  cart[atom*3+2] = f2*cz;
}

// ---------------- edge geometry: 16 edges/block, 16 thr/edge x 8 rbf cols
__global__ __launch_bounds__(256) void k_edge(
    const float* __restrict__ cart, const int* __restrict__ src,
    const int* __restrict__ dst, float* __restrict__ unit,
    __hip_bfloat16* __restrict__ rbf) {
  int t = threadIdx.x;
  int e = blockIdx.x * 16 + (t >> 4);
  int cg = t & 15;                       // col group: cols cg*8 .. cg*8+7
  int s = src[e], d = dst[e];
  float dx = cart[d*3+0] - cart[s*3+0];
  float dy = cart[d*3+1] - cart[s*3+1];
  float dz = cart[d*3+2] - cart[s*3+2];
  float dd = sqrtf(dx*dx + dy*dy + dz*dz + 1e-12f);
  float inv = 1.f / dd;
  if (cg == 0) {
    unit[e*3+0] = dx*inv; unit[e*3+1] = dy*inv; unit[e*3+2] = dz*inv;
  }
  float env = 0.5f * (cosf(PI_F * fminf(dd * (1.f/CUT_F), 1.f)) + 1.f);
  __hip_bfloat16 v8[8];
#pragma unroll
  for (int u = 0; u < 8; ++u) {
    int j = cg*8 + u;
    float tt = (dd - (float)j * (CUT_F/(NRBF-1))) * ((NRBF-1)/CUT_F);
    v8[u] = f2bf(expf(-tt*tt) * env);
  }
  *(uint4*)(rbf + (size_t)e*NRBF + cg*8) = *(uint4*)v8;
}

// ----------------- weights: transpose + cast to bf16, W_T[n][k] = W[k][n]
__global__ void k_wcast(const float* __restrict__ W_edge, const float* __restrict__ Wb_upd,
                        const float* __restrict__ Wb_msg, const float* __restrict__ Wb_rbf,
                        __hip_bfloat16* __restrict__ WT) {
  int idx = blockIdx.x * 256 + threadIdx.x;
  if (idx < 196608) {
    int j = idx / 49152, t = idx % 49152;
    int n = t / 384, k = t % 384;
    const float* srcW = (j == 0) ? W_edge : (Wb_upd + (j-1)*49152);
    WT[idx] = f2bf(srcW[k*128 + n]);
  } else {
    int t = idx - 196608;
    int j = t / 16384, q = t % 16384;
    int n = q / 128, k = q % 128;
    const float* srcW = (j < 3) ? (Wb_msg + j*16384) : (Wb_rbf + (j-3)*16384);
    WT[idx] = f2bf(srcW[k*128 + n]);
  }
}

// --------------------------------------------------- 8-row block GEMM helper
template<int KD>
__device__ __forceinline__ void gemm8(const float* __restrict__ W,
                                      const float (*in)[KD], float acc[8], int tid) {
#pragma unroll 2
  for (int k4 = 0; k4 < KD/4; ++k4) {
    float w0 = W[(k4*4+0)*HID + tid];
    float w1 = W[(k4*4+1)*HID + tid];
    float w2 = W[(k4*4+2)*HID + tid];
    float w3 = W[(k4*4+3)*HID + tid];
#pragma unroll
    for (int r = 0; r < 8; ++r) {
      const float4 v = *reinterpret_cast<const float4*>(&in[r][k4*4]);
      acc[r] = fmaf(v.x, w0, acc[r]);
      acc[r] = fmaf(v.y, w1, acc[r]);
      acc[r] = fmaf(v.z, w2, acc[r]);
      acc[r] = fmaf(v.w, w3, acc[r]);
    }
  }
}

// --------------------------------------------------------- h = relu([emb|z]W)
__global__ __launch_bounds__(128) void k_h(
    const int* __restrict__ atype, const float* __restrict__ z,
    const float* __restrict__ emb, const float* __restrict__ W,
    const float* __restrict__ b, float* __restrict__ h,
    __hip_bfloat16* __restrict__ h_bf) {
  __shared__ __align__(16) float in[8][384];
  int tid = threadIdx.x;
  int row0 = blockIdx.x * 8;
#pragma unroll
  for (int r = 0; r < 8; ++r) {
    int atom = row0 + r;
    in[r][tid]     = emb[atype[atom]*HID + tid];
    int cb = (atom >> 6) * LAT;
    in[r][tid+128] = z[cb + tid];
    in[r][tid+256] = z[cb + 128 + tid];
  }
  __syncthreads();
  float acc[8] = {0,0,0,0,0,0,0,0};
  gemm8<384>(W, in, acc, tid);
  float bias = b[tid];
#pragma unroll
  for (int r = 0; r < 8; ++r) {
    float v = fmaxf(acc[r] + bias, 0.f);
    h[(row0+r)*HID + tid] = v;
    h_bf[(row0+r)*HID + tid] = f2bf(v);
  }
}

// ============ MFMA edge GEMM, LDS-free / barrier-free.
// out = bf16( [mode1: third +] relu([h_s|h_d|third]@W + b) )
// 256 thr = 4 waves x 32 rows (2 m-tiles); A-frags loaded DIRECT from global.
__global__ __launch_bounds__(256) void k_egemm(
    const int* __restrict__ src, const int* __restrict__ dst,
    const __hip_bfloat16* __restrict__ h_bf,
    const __hip_bfloat16* __restrict__ third,   // rbf (mode0) or m (mode1)
    const __hip_bfloat16* __restrict__ WT,      // [128][384] bf16, n-major
    const float* __restrict__ b,
    __hip_bfloat16* __restrict__ out, int mode) {
  const int tid = threadIdx.x;
  const int w = tid >> 6, lane = tid & 63, ln = lane & 15, qd = lane >> 4;
  const int row0 = blockIdx.x * 128 + w * 32;   // this wave's 32 rows

  const int r_a = row0 + ln;         // m-tile 0 row for this lane
  const int r_b = row0 + 16 + ln;    // m-tile 1 row
  const short* hsA = (const short*)h_bf + (size_t)src[r_a]*HID;
  const short* hdA = (const short*)h_bf + (size_t)dst[r_a]*HID;
  const short* thA = (const short*)third + (size_t)r_a*HID;
  const short* hsB = (const short*)h_bf + (size_t)src[r_b]*HID;
  const short* hdB = (const short*)h_bf + (size_t)dst[r_b]*HID;
  const short* thB = (const short*)third + (size_t)r_b*HID;

  const short* Wb = (const short*)WT + ln*384 + qd*8;

  f32x4 acc0[8], acc1[8];
#pragma unroll
  for (int ct = 0; ct < 8; ++ct) { acc0[ct] = (f32x4){0,0,0,0}; acc1[ct] = (f32x4){0,0,0,0}; }

#define SEG(qa, qb, ksb)                                                        \
  _Pragma("unroll")                                                             \
  for (int k2 = 0; k2 < 4; ++k2) {                                              \
    short8 aA = *(const short8*)((qa) + k2*32 + qd*8);                          \
    short8 aB = *(const short8*)((qb) + k2*32 + qd*8);                          \
    _Pragma("unroll")                                                           \
    for (int ct = 0; ct < 8; ++ct) {                                            \
      short8 bb = *(const short8*)(Wb + ct*6144 + ((ksb)+k2)*32);               \
      acc0[ct] = __builtin_amdgcn_mfma_f32_16x16x32_bf16(aA, bb, acc0[ct],0,0,0);\
      acc1[ct] = __builtin_amdgcn_mfma_f32_16x16x32_bf16(aB, bb, acc1[ct],0,0,0);\
    }                                                                           \
  }

  SEG(hsA, hsB, 0)
  SEG(hdA, hdB, 4)
  SEG(thA, thB, 8)
#undef SEG

#pragma unroll
  for (int mt = 0; mt < 2; ++mt) {
    const f32x4* acc = mt ? acc1 : acc0;
#pragma unroll
    for (int ct = 0; ct < 8; ++ct) {
      float bias = b[ct*16 + ln];
      int col = ct*16 + ln;
#pragma unroll
      for (int reg = 0; reg < 4; ++reg) {
        int row = row0 + mt*16 + qd*4 + reg;
        float v = fmaxf(acc[ct][reg] + bias, 0.f);
        if (mode) v += bf2f(((const __hip_bfloat16*)third)[(size_t)row*HID + col]);
        out[(size_t)row*HID + col] = f2bf(v);
      }
    }
  }
}

// ===== fused msg+segsum, 4 partial blocks per crystal -> aggP slices.
// aggP[p][atom][col]; block (c,p) handles edges c*1280 + p*320 .. +320
// 512 thr = 8 waves; 20 tiles of 16 edges; wave w: tiles w, w+8, w+16.
__global__ __launch_bounds__(512) void k_msgagg(
    const __hip_bfloat16* __restrict__ m, const __hip_bfloat16* __restrict__ rbf,
    const __hip_bfloat16* __restrict__ WmT, const float* __restrict__ bm,
    const __hip_bfloat16* __restrict__ WgT, const int* __restrict__ dst,
    float* __restrict__ aggP) {
  __shared__ float agg[64 * 132];     // 33 KB; pitch 132 spreads rows over banks
  const int tid = threadIdx.x;
  const int c = blockIdx.x & 255, pq = blockIdx.x >> 8;
  const int w = tid >> 6, lane = tid & 63, ln = lane & 15, qd = lane >> 4;

  for (int i = tid; i < 64*132; i += 512) agg[i] = 0.f;

  float bias[8];
#pragma unroll
  for (int ct = 0; ct < 8; ++ct) bias[ct] = bm[ct*16 + ln];
  __syncthreads();

  for (int it = 0; it < 3; ++it) {
    int s = w + it*8;
    if (s >= 20) break;
    int e0 = c * 1280 + pq * 320 + s * 16;
    const short* pm = (const short*)m   + (size_t)(e0 + ln)*HID + qd*8;
    const short* pr = (const short*)rbf + (size_t)(e0 + ln)*HID + qd*8;
    short8 am[4], ar[4];
#pragma unroll
    for (int ks = 0; ks < 4; ++ks) {
      am[ks] = *(const short8*)(pm + ks*32);
      ar[ks] = *(const short8*)(pr + ks*32);
    }
    int d4[4];
#pragma unroll
    for (int reg = 0; reg < 4; ++reg) d4[reg] = dst[e0 + qd*4 + reg] & 63;

    f32x4 accM[8], accG[8];
#pragma unroll
    for (int ct = 0; ct < 8; ++ct) { accM[ct] = (f32x4){0,0,0,0}; accG[ct] = (f32x4){0,0,0,0}; }
#pragma unroll
    for (int ct = 0; ct < 8; ++ct) {
      const short* bmp = (const short*)WmT + (ct*16 + ln)*128 + qd*8;
      const short* bgp = (const short*)WgT + (ct*16 + ln)*128 + qd*8;
#pragma unroll
      for (int ks = 0; ks < 4; ++ks) {
        accM[ct] = __builtin_amdgcn_mfma_f32_16x16x32_bf16(am[ks], *(const short8*)(bmp + ks*32), accM[ct], 0,0,0);
        accG[ct] = __builtin_amdgcn_mfma_f32_16x16x32_bf16(ar[ks], *(const short8*)(bgp + ks*32), accG[ct], 0,0,0);
      }
    }
#pragma unroll
    for (int ct = 0; ct < 8; ++ct) {
#pragma unroll
      for (int reg = 0; reg < 4; ++reg) {
        float v = fmaxf(accM[ct][reg] + bias[ct], 0.f) * accG[ct][reg];
        atomicAdd(&agg[d4[reg]*132 + ct*16 + ln], v);
      }
    }
  }
  __syncthreads();
  float* outp = aggP + ((size_t)pq * NATOMS + c * 64) * HID;
  for (int i = tid; i < 64*128; i += 512) {
    int a = i >> 7, col = i & 127;
    outp[a*HID + col] = agg[a*132 + col];
  }
}

// ------------- dense-row K=128 GEMM: Y = relu(sum_parts(X)@W+b) [+=Y mode 1]
__global__ __launch_bounds__(128) void k_fc(
    const float* __restrict__ X, const float* __restrict__ W,
    const float* __restrict__ b, float* __restrict__ Y,
    __hip_bfloat16* __restrict__ Ybf, int mode, int parts) {
  __shared__ __align__(16) float ix[8][128];
  int tid = threadIdx.x;
  int row0 = blockIdx.x * 8;
#pragma unroll
  for (int r = 0; r < 8; ++r) {
    float v = X[(size_t)(row0+r)*HID + tid];
    for (int p = 1; p < parts; ++p)
      v += X[(size_t)p*NATOMS*HID + (size_t)(row0+r)*HID + tid];
    ix[r][tid] = v;
  }
  __syncthreads();
  float acc[8] = {0,0,0,0,0,0,0,0};
  gemm8<128>(W, ix, acc, tid);
  float bias = b[tid];
#pragma unroll
  for (int r = 0; r < 8; ++r) {
    float v = fmaxf(acc[r] + bias, 0.f);
    int o = (row0+r)*HID + tid;
    if (mode) {
      v += Y[o];
      Ybf[o] = f2bf(v);
    }
    Y[o] = v;
  }
}

// ------------------------------------------------- f = m @ W_force + b_force
__global__ void k_force(const __hip_bfloat16* __restrict__ m,
                        const float* __restrict__ Wf,
                        const float* __restrict__ bf, float* __restrict__ f) {
  int lane = threadIdx.x & 63;
  int wave = threadIdx.x >> 6;
  int ebase = blockIdx.x * 64 + wave * 16;
  float w0 = Wf[lane], w1 = Wf[64 + lane];
  float b = bf[0];
  for (int t = 0; t < 16; ++t) {
    int e = ebase + t;
    float p = bf2f(m[(size_t)e*HID + lane]) * w0 + bf2f(m[(size_t)e*HID + 64 + lane]) * w1;
#pragma unroll
    for (int off = 32; off > 0; off >>= 1) p += __shfl_down(p, off, 64);
    if (lane == 0) f[e] = p + b;
  }
}

// ----------------------------------- pred_cart = segsum(f*unit) per crystal
__global__ void k_pcart(const float* __restrict__ f, const float* __restrict__ unit,
                        const int* __restrict__ dst, float* __restrict__ out) {
  __shared__ float acc[AATOMS * 3];
  int c = blockIdx.x, tid = threadIdx.x;  // 256 threads
  if (tid < AATOMS*3) acc[tid] = 0.f;
  __syncthreads();
  for (int t = tid; t < 1280; t += 256) {
    int e = c*1280 + t;
    int d = dst[e] & 63;
    float fv = f[e];
    atomicAdd(&acc[d*3+0], fv * unit[e*3+0]);
    atomicAdd(&acc[d*3+1], fv * unit[e*3+1]);
    atomicAdd(&acc[d*3+2], fv * unit[e*3+2]);
  }
  __syncthreads();
  if (tid < AATOMS*3) out[c*AATOMS*3 + tid] = acc[tid];
}

// ----------------------------------------- final fc3: (128 -> 2) per atom row
__global__ void k_fc3(const float* __restrict__ a2, const float* __restrict__ W,
                      const float* __restrict__ b, float* __restrict__ out) {
  int lane = threadIdx.x & 63;
  int wave = threadIdx.x >> 6;
  int row = blockIdx.x * 4 + wave;
  float x0 = a2[row*HID + lane], x1 = a2[row*HID + 64 + lane];
  float p0 = x0 * W[lane*2+0] + x1 * W[(64+lane)*2+0];
  float p1 = x0 * W[lane*2+1] + x1 * W[(64+lane)*2+1];
#pragma unroll
  for (int off = 32; off > 0; off >>= 1) {
    p0 += __shfl_down(p0, off, 64);
    p1 += __shfl_down(p1, off, 64);
  }
  if (lane == 0) {
    out[row*2+0] = p0 + b[0];
    out[row*2+1] = p1 + b[1];
  }
}

extern "C" void kernel_launch(void* const* d_in, const int* in_sizes, int n_in,
                              void* d_out, int out_size, void* d_ws, size_t ws_size,
                              hipStream_t stream) {
  const float* z        = (const float*)d_in[0];
  const float* frac     = (const float*)d_in[1];
  const float* lengths  = (const float*)d_in[2];
  const float* angles   = (const float*)d_in[3];
  const int*   atype    = (const int*)  d_in[4];
  const int*   src      = (const int*)  d_in[5];
  const int*   dst      = (const int*)  d_in[6];
  const float* emb      = (const float*)d_in[7];
  const float* W_in     = (const float*)d_in[8];
  const float* b_in     = (const float*)d_in[9];
  const float* W_edge   = (const float*)d_in[10];
  const float* b_edge   = (const float*)d_in[11];
  const float* Wb_rbf   = (const float*)d_in[12];
  const float* Wb_msg   = (const float*)d_in[13];
  const float* bb_msg   = (const float*)d_in[14];
  const float* Wb_atom  = (const float*)d_in[15];
  const float* bb_atom  = (const float*)d_in[16];
  const float* Wb_upd   = (const float*)d_in[17];
  const float* bb_upd   = (const float*)d_in[18];
  const float* W_force  = (const float*)d_in[19];
  const float* b_force  = (const float*)d_in[20];
  const float* W_fc1    = (const float*)d_in[21];
  const float* b_fc1    = (const float*)d_in[22];
  const float* W_fc2    = (const float*)d_in[23];
  const float* b_fc2    = (const float*)d_in[24];
  const float* W_fc3    = (const float*)d_in[25];
  const float* b_fc3    = (const float*)d_in[26];

  // ---- workspace layout (~219 MB) ----
  char* p = (char*)d_ws;
  float* cart = (float*)p;            p += (size_t)NATOMS*3*4;
  float* unit = (float*)p;            p += (size_t)NEDGE*3*4;
  float* h    = (float*)p;            p += (size_t)NATOMS*HID*4;
  float* aggP = (float*)p;            p += (size_t)NPART*NATOMS*HID*4;  // 33.6 MB
  __hip_bfloat16* h_bf = (__hip_bfloat16*)p; p += (size_t)NATOMS*HID*2;
  __hip_bfloat16* m    = (__hip_bfloat16*)p; p += (size_t)NEDGE*HID*2;   // 84 MB
  __hip_bfloat16* rbf  = (__hip_bfloat16*)p; p += (size_t)NEDGE*NRBF*2;  // 84 MB
  __hip_bfloat16* WT   = (__hip_bfloat16*)p; p += (size_t)294912*2;
  // rbf region dead after last k_msgagg -> overlay epilogue scratch
  float* f  = (float*)rbf;
  float* a1 = f + NEDGE;
  float* a2 = a1 + NATOMS*HID;

  __hip_bfloat16* WT_edge = WT;                    // 128x384
  __hip_bfloat16* WT_upd0 = WT + 49152;            // 3 x 128x384
  __hip_bfloat16* WT_msg0 = WT + 196608;           // 3 x 128x128
  __hip_bfloat16* WT_rbf0 = WT + 245760;           // 3 x 128x128

  float* out_cart = (float*)d_out;
  float* out_at   = out_cart + NATOMS*3;

  k_wcast<<<1152, 256, 0, stream>>>(W_edge, Wb_upd, Wb_msg, Wb_rbf, WT);
  k_cart<<<NATOMS/256, 256, 0, stream>>>(frac, lengths, angles, cart);
  k_edge<<<NEDGE/16, 256, 0, stream>>>(cart, src, dst, unit, rbf);
  k_h<<<NATOMS/8, 128, 0, stream>>>(atype, z, emb, W_in, b_in, h, h_bf);
  k_egemm<<<NEDGE/128, 256, 0, stream>>>(src, dst, h_bf, rbf, WT_edge, b_edge, m, 0);

  for (int i = 0; i < NBLK; ++i) {
    k_msgagg<<<NCRYST*NPART, 512, 0, stream>>>(m, rbf, WT_msg0 + i*16384, bb_msg + i*HID,
                                               WT_rbf0 + i*16384, dst, aggP);
    k_fc<<<NATOMS/8, 128, 0, stream>>>(aggP, Wb_atom + i*HID*HID, bb_atom + i*HID,
                                       h, h_bf, 1, NPART);
    k_egemm<<<NEDGE/128, 256, 0, stream>>>(src, dst, h_bf, m, WT_upd0 + i*49152,
                                           bb_upd + i*HID, m, 1);
  }

  k_force<<<NEDGE/64, 256, 0, stream>>>(m, W_force, b_force, f);
  k_pcart<<<NCRYST, 256, 0, stream>>>(f, unit, dst, out_cart);
  k_fc<<<NATOMS/8, 128, 0, stream>>>(h, W_fc1, b_fc1, a1, nullptr, 0, 1);
  k_fc<<<NATOMS/8, 128, 0, stream>>>(a1, W_fc2, b_fc2, a2, nullptr, 0, 1);
  k_fc3<<<NATOMS/4, 256, 0, stream>>>(a2, W_fc3, b_fc3, out_at);
}

// Round 8
// 1488.194 us; speedup vs baseline: 1.3183x; 1.3183x over previous
//
#include <hip/hip_runtime.h>
#include <hip/hip_bf16.h>

#define NCRYST 256
#define AATOMS 64
#define KNBR   20
#define HID    128
#define LAT    256
#define NRBF   128
#define NBLK   3
#define NATOMS (NCRYST * AATOMS)   // 16384
#define NEDGE  (NATOMS * KNBR)     // 327680
#define NPART  4                   // agg partial slices per crystal
#define DQ     4096                // dist-table knots over [0, CUT]
#define PI_F   3.14159265358979323846f
#define CUT_F  6.0f

typedef short short8 __attribute__((ext_vector_type(8)));   // 8 bf16 (4 VGPRs)
typedef float f32x4  __attribute__((ext_vector_type(4)));   // MFMA C/D

__device__ __forceinline__ float bf2f(__hip_bfloat16 x) { return __bfloat162float(x); }
__device__ __forceinline__ __hip_bfloat16 f2bf(float x) { return __float2bfloat16(x); }
__device__ __forceinline__ float s2f(short x) {
  return __uint_as_float(((unsigned)(unsigned short)x) << 16);
}
__device__ __forceinline__ short f2s(float x) {
  union { short s; __hip_bfloat16 b; } u; u.b = f2bf(x); return u.s;
}

// lerp lookup in a [DQ][128] f32 table; exact 0 for d >= CUT (matches env==0)
__device__ __forceinline__ float tlook(const float* __restrict__ T, float d, int col) {
  if (d >= CUT_F) return 0.f;
  float x = d * ((float)(DQ - 1) / CUT_F);
  int i0 = (int)x;
  float fr = x - (float)i0;
  float v0 = T[i0 * 128 + col];
  float v1 = T[(i0 + 1) * 128 + col];
  return fmaf(fr, v1 - v0, v0);
}

// ---------------------------------------------------------------- cart coords
__global__ void k_cart(const float* __restrict__ frac, const float* __restrict__ lengths,
                       const float* __restrict__ angles, float* __restrict__ cart) {
  int atom = blockIdx.x * blockDim.x + threadIdx.x;
  if (atom >= NATOMS) return;
  int c = atom >> 6;
  float al = angles[c*3+0] * (PI_F/180.f);
  float be = angles[c*3+1] * (PI_F/180.f);
  float ga = angles[c*3+2] * (PI_F/180.f);
  float ca = cosf(al), cb = cosf(be), cg = cosf(ga), sg = sinf(ga);
  float a = lengths[c*3+0], b = lengths[c*3+1], cl = lengths[c*3+2];
  float cx = cl * cb;
  float cy = cl * (ca - cb*cg) / sg;
  float cz = sqrtf(fmaxf(cl*cl - cx*cx - cy*cy, 1e-8f));
  float f0 = frac[atom*3+0], f1 = frac[atom*3+1], f2 = frac[atom*3+2];
  cart[atom*3+0] = f0*a + f1*(b*cg) + f2*cx;
  cart[atom*3+1] = f1*(b*sg) + f2*cy;
  cart[atom*3+2] = f2*cz;
}

// ---------------- edge geometry: unit + dist only (rbf is now a table)
__global__ void k_edge(const float* __restrict__ cart, const int* __restrict__ src,
                       const int* __restrict__ dst, float* __restrict__ unit,
                       float* __restrict__ dist) {
  int e = blockIdx.x * blockDim.x + threadIdx.x;
  if (e >= NEDGE) return;
  int s = src[e], d = dst[e];
  float dx = cart[d*3+0] - cart[s*3+0];
  float dy = cart[d*3+1] - cart[s*3+1];
  float dz = cart[d*3+2] - cart[s*3+2];
  float dd = sqrtf(dx*dx + dy*dy + dz*dz + 1e-12f);
  float inv = 1.f / dd;
  dist[e] = dd;
  unit[e*3+0] = dx*inv; unit[e*3+1] = dy*inv; unit[e*3+2] = dz*inv;
}

// ---------------- dist tables: T[0]=rbf@W_edge[256:384], T[1+i]=rbf@Wb_rbf[i]
__global__ __launch_bounds__(128) void k_tab(const float* __restrict__ W_edge,
                                             const float* __restrict__ Wb_rbf,
                                             float* __restrict__ T) {
  int q = blockIdx.x, n = threadIdx.x;
  __shared__ float rv[128];
  float d = (float)q * (CUT_F / (float)(DQ - 1));
  float env = 0.5f * (cosf(PI_F * fminf(d * (1.f/CUT_F), 1.f)) + 1.f);
  float t = (d - (float)n * (CUT_F/(NRBF-1))) * ((NRBF-1)/CUT_F);
  rv[n] = expf(-t*t) * env;
  __syncthreads();
  float a0 = 0.f, a1 = 0.f, a2 = 0.f, a3 = 0.f;
  for (int j = 0; j < 128; ++j) {
    float r = rv[j];
    a0 = fmaf(r, W_edge[(256 + j)*128 + n], a0);
    a1 = fmaf(r, Wb_rbf[0*16384 + j*128 + n], a1);
    a2 = fmaf(r, Wb_rbf[1*16384 + j*128 + n], a2);
    a3 = fmaf(r, Wb_rbf[2*16384 + j*128 + n], a3);
  }
  T[(0*DQ + q)*128 + n] = a0;
  T[(1*DQ + q)*128 + n] = a1;
  T[(2*DQ + q)*128 + n] = a2;
  T[(3*DQ + q)*128 + n] = a3;
}

// ----------------- weights: transpose + cast to bf16 (n-major)
// layout (elems): WT_in 0 | WT_edge 49152 | WT_upd 81920 | WT_msg 229376 |
//                 WT_atom 278528 | WT_fc1 327680 | WT_fc2 344064 | end 360448
__global__ void k_wcast(const float* __restrict__ W_in, const float* __restrict__ W_edge,
                        const float* __restrict__ Wb_upd, const float* __restrict__ Wb_msg,
                        const float* __restrict__ Wb_atom, const float* __restrict__ W_fc1,
                        const float* __restrict__ W_fc2, __hip_bfloat16* __restrict__ WT) {
  int idx = blockIdx.x * 256 + threadIdx.x;
  if (idx >= 360448) return;
  int t = idx; const float* S; int K;
  if (t < 49152)                { S = W_in;  K = 384; }
  else if ((t -= 49152) < 32768)  { S = W_edge; K = 256; }
  else if ((t -= 32768) < 147456) { S = Wb_upd + (t/49152)*49152; t %= 49152; K = 384; }
  else if ((t -= 147456) < 49152) { S = Wb_msg + (t/16384)*16384; t %= 16384; K = 128; }
  else if ((t -= 49152) < 49152)  { S = Wb_atom + (t/16384)*16384; t %= 16384; K = 128; }
  else if ((t -= 49152) < 16384)  { S = W_fc1; K = 128; }
  else                            { t -= 16384; S = W_fc2; K = 128; }
  int n = t / K, k = t % K;
  WT[idx] = f2bf(S[k*128 + n]);
}

// ============ MFMA h: h = relu([emb[atype]|z]@W_in + b), 64 rows/block
__global__ __launch_bounds__(256) void k_hm(
    const int* __restrict__ atype, const float* __restrict__ z,
    const float* __restrict__ emb, const __hip_bfloat16* __restrict__ WTin,
    const float* __restrict__ b, float* __restrict__ h,
    __hip_bfloat16* __restrict__ h_bf) {
  const int tid = threadIdx.x;
  const int w = tid >> 6, lane = tid & 63, ln = lane & 15, qd = lane >> 4;
  const int row0w = blockIdx.x * 64 + w * 16;
  const int arow = row0w + ln;
  const float* esrc = emb + (size_t)atype[arow] * 128;
  const float* zsrc = z + (size_t)(arow >> 6) * LAT;

  short8 af[12];
#pragma unroll
  for (int ks = 0; ks < 4; ++ks) {
    float4 v0 = *(const float4*)(esrc + ks*32 + qd*8);
    float4 v1 = *(const float4*)(esrc + ks*32 + qd*8 + 4);
    af[ks] = (short8){f2s(v0.x),f2s(v0.y),f2s(v0.z),f2s(v0.w),
                      f2s(v1.x),f2s(v1.y),f2s(v1.z),f2s(v1.w)};
  }
#pragma unroll
  for (int ks = 4; ks < 12; ++ks) {
    float4 v0 = *(const float4*)(zsrc + (ks-4)*32 + qd*8);
    float4 v1 = *(const float4*)(zsrc + (ks-4)*32 + qd*8 + 4);
    af[ks] = (short8){f2s(v0.x),f2s(v0.y),f2s(v0.z),f2s(v0.w),
                      f2s(v1.x),f2s(v1.y),f2s(v1.z),f2s(v1.w)};
  }

  const short* Wb = (const short*)WTin + ln*384 + qd*8;
  f32x4 acc[8];
#pragma unroll
  for (int ct = 0; ct < 8; ++ct) acc[ct] = (f32x4){0,0,0,0};
#pragma unroll
  for (int ks = 0; ks < 12; ++ks)
#pragma unroll
    for (int ct = 0; ct < 8; ++ct)
      acc[ct] = __builtin_amdgcn_mfma_f32_16x16x32_bf16(af[ks],
                  *(const short8*)(Wb + ct*16*384 + ks*32), acc[ct], 0,0,0);

#pragma unroll
  for (int ct = 0; ct < 8; ++ct) {
    int col = ct*16 + ln;
    float bias = b[col];
#pragma unroll
    for (int reg = 0; reg < 4; ++reg) {
      int crow = row0w + qd*4 + reg;
      float v = fmaxf(acc[ct][reg] + bias, 0.f);
      size_t o = (size_t)crow*128 + col;
      h[o] = v;
      h_bf[o] = f2bf(v);
    }
  }
}

// ============ MFMA edge GEMM, LDS/barrier-free; 4 waves x 32 rows.
// MODE 0: out = bf16(relu(hs@W1 + hd@W2 + T0(d) + b))         (KD=256)
// MODE 1: out = bf16(m + relu([hs|hd|m]@W + b))               (KD=384)
// MODE 2: MODE1 value v, NO m store; f[row] = v.Wf + bf       (KD=384)
template<int KD, int MODE>
__global__ __launch_bounds__(256) void k_egemm(
    const int* __restrict__ src, const int* __restrict__ dst,
    const __hip_bfloat16* __restrict__ h_bf,
    const __hip_bfloat16* __restrict__ m_in,
    const float* __restrict__ dist, const float* __restrict__ T0,
    const __hip_bfloat16* __restrict__ WT, const float* __restrict__ b,
    __hip_bfloat16* __restrict__ out,
    const float* __restrict__ Wf, const float* __restrict__ bfrc,
    float* __restrict__ fout) {
  const int tid = threadIdx.x;
  const int w = tid >> 6, lane = tid & 63, ln = lane & 15, qd = lane >> 4;
  const int row0 = blockIdx.x * 128 + w * 32;

  const int r_a = row0 + ln, r_b = row0 + 16 + ln;
  const short* hsA = (const short*)h_bf + (size_t)src[r_a]*HID;
  const short* hdA = (const short*)h_bf + (size_t)dst[r_a]*HID;
  const short* hsB = (const short*)h_bf + (size_t)src[r_b]*HID;
  const short* hdB = (const short*)h_bf + (size_t)dst[r_b]*HID;

  const short* Wb = (const short*)WT + ln*KD + qd*8;

  f32x4 acc0[8], acc1[8];
#pragma unroll
  for (int ct = 0; ct < 8; ++ct) { acc0[ct] = (f32x4){0,0,0,0}; acc1[ct] = (f32x4){0,0,0,0}; }

#define SEG(qa, qb, ksb)                                                        \
  _Pragma("unroll")                                                             \
  for (int k2 = 0; k2 < 4; ++k2) {                                              \
    short8 aA = *(const short8*)((qa) + k2*32 + qd*8);                          \
    short8 aB = *(const short8*)((qb) + k2*32 + qd*8);                          \
    _Pragma("unroll")                                                           \
    for (int ct = 0; ct < 8; ++ct) {                                            \
      short8 bb = *(const short8*)(Wb + ct*16*KD + ((ksb)+k2)*32);              \
      acc0[ct] = __builtin_amdgcn_mfma_f32_16x16x32_bf16(aA, bb, acc0[ct],0,0,0);\
      acc1[ct] = __builtin_amdgcn_mfma_f32_16x16x32_bf16(aB, bb, acc1[ct],0,0,0);\
    }                                                                           \
  }

  SEG(hsA, hsB, 0)
  SEG(hdA, hdB, 4)
  if constexpr (MODE >= 1) {
    const short* thA = (const short*)m_in + (size_t)r_a*HID;
    const short* thB = (const short*)m_in + (size_t)r_b*HID;
    SEG(thA, thB, 8)
  }
#undef SEG

  float bias8[8], wf8[8];
#pragma unroll
  for (int ct = 0; ct < 8; ++ct) bias8[ct] = b[ct*16 + ln];
  if constexpr (MODE == 2) {
#pragma unroll
    for (int ct = 0; ct < 8; ++ct) wf8[ct] = Wf[ct*16 + ln];
  }
  float bF = (MODE == 2) ? bfrc[0] : 0.f;

#pragma unroll
  for (int mt = 0; mt < 2; ++mt) {
    const f32x4* acc = mt ? acc1 : acc0;
#pragma unroll
    for (int reg = 0; reg < 4; ++reg) {
      int row = row0 + mt*16 + qd*4 + reg;
      float dr = 0.f;
      if constexpr (MODE == 0) dr = dist[row];
      float fp = 0.f;
#pragma unroll
      for (int ct = 0; ct < 8; ++ct) {
        int col = ct*16 + ln;
        float v;
        if constexpr (MODE == 0) {
          v = fmaxf(acc[ct][reg] + bias8[ct] + tlook(T0, dr, col), 0.f);
        } else {
          v = fmaxf(acc[ct][reg] + bias8[ct], 0.f)
              + bf2f(m_in[(size_t)row*HID + col]);
        }
        if constexpr (MODE != 2) out[(size_t)row*HID + col] = f2bf(v);
        if constexpr (MODE == 2) fp = fmaf(v, wf8[ct], fp);
      }
      if constexpr (MODE == 2) {
        fp += __shfl_xor(fp, 1, 64);
        fp += __shfl_xor(fp, 2, 64);
        fp += __shfl_xor(fp, 4, 64);
        fp += __shfl_xor(fp, 8, 64);
        if (ln == 0) fout[row] = fp + bF;
      }
    }
  }
}

// ===== fused msg+segsum, NPART partial blocks per crystal -> bf16 aggP slices
// msg = relu(m@Wm+bm) * gate(d);  gate via table lerp.  512 thr = 8 waves.
__global__ __launch_bounds__(512) void k_msgagg(
    const __hip_bfloat16* __restrict__ m, const float* __restrict__ dist,
    const __hip_bfloat16* __restrict__ WmT, const float* __restrict__ bm,
    const float* __restrict__ Tg, const int* __restrict__ dst,
    __hip_bfloat16* __restrict__ aggP) {
  __shared__ float agg[64 * 132];
  const int tid = threadIdx.x;
  const int c = blockIdx.x & 255, pq = blockIdx.x >> 8;
  const int w = tid >> 6, lane = tid & 63, ln = lane & 15, qd = lane >> 4;

  for (int i = tid; i < 64*132; i += 512) agg[i] = 0.f;
  float bias8[8];
#pragma unroll
  for (int ct = 0; ct < 8; ++ct) bias8[ct] = bm[ct*16 + ln];
  __syncthreads();

  for (int it = 0; it < 3; ++it) {
    int s = w + it*8;
    if (s >= 20) break;
    int e0 = c * 1280 + pq * 320 + s * 16;
    const short* pm = (const short*)m + (size_t)(e0 + ln)*HID + qd*8;
    short8 am[4];
#pragma unroll
    for (int ks = 0; ks < 4; ++ks) am[ks] = *(const short8*)(pm + ks*32);
    int d4[4]; float dd4[4];
#pragma unroll
    for (int reg = 0; reg < 4; ++reg) {
      d4[reg] = dst[e0 + qd*4 + reg] & 63;
      dd4[reg] = dist[e0 + qd*4 + reg];
    }
    f32x4 accM[8];
#pragma unroll
    for (int ct = 0; ct < 8; ++ct) accM[ct] = (f32x4){0,0,0,0};
#pragma unroll
    for (int ct = 0; ct < 8; ++ct) {
      const short* bmp = (const short*)WmT + (ct*16 + ln)*128 + qd*8;
#pragma unroll
      for (int ks = 0; ks < 4; ++ks)
        accM[ct] = __builtin_amdgcn_mfma_f32_16x16x32_bf16(am[ks],
                     *(const short8*)(bmp + ks*32), accM[ct], 0,0,0);
    }
#pragma unroll
    for (int ct = 0; ct < 8; ++ct) {
      int col = ct*16 + ln;
#pragma unroll
      for (int reg = 0; reg < 4; ++reg) {
        float g = tlook(Tg, dd4[reg], col);
        float v = fmaxf(accM[ct][reg] + bias8[ct], 0.f) * g;
        if (v != 0.f) atomicAdd(&agg[d4[reg]*132 + col], v);
      }
    }
  }
  __syncthreads();
  __hip_bfloat16* outp = aggP + ((size_t)pq * NATOMS + c * 64) * HID;
  for (int i = tid; i < 64*128; i += 512) {
    int a = i >> 7, col = i & 127;
    outp[a*HID + col] = f2bf(agg[a*132 + col]);
  }
}

// ============ MFMA fc (K=128): Y = [res +] relu(A@W + b); A = single bf16 or
// sum of NPART bf16 slices. 4 waves x 16 rows, 64 rows/block.
__global__ __launch_bounds__(256) void k_fcm(
    const __hip_bfloat16* __restrict__ A,       // nslice==1
    const __hip_bfloat16* __restrict__ slices,  // nslice==NPART
    int nslice,
    const __hip_bfloat16* __restrict__ WT, const float* __restrict__ b,
    const float* __restrict__ resIn,            // nullable
    float* __restrict__ Yf,                     // nullable
    __hip_bfloat16* __restrict__ Ybf) {         // nullable
  const int tid = threadIdx.x;
  const int w = tid >> 6, lane = tid & 63, ln = lane & 15, qd = lane >> 4;
  const int row0w = blockIdx.x * 64 + w * 16;
  const int arow = row0w + ln;

  short8 af[4];
  if (nslice == 1) {
    const short* pa = (const short*)A + (size_t)arow*128 + qd*8;
#pragma unroll
    for (int ks = 0; ks < 4; ++ks) af[ks] = *(const short8*)(pa + ks*32);
  } else {
#pragma unroll
    for (int ks = 0; ks < 4; ++ks) {
      float s[8] = {0,0,0,0,0,0,0,0};
#pragma unroll
      for (int p = 0; p < NPART; ++p) {
        short8 v = *(const short8*)((const short*)slices +
                     (size_t)p*NATOMS*128 + (size_t)arow*128 + qd*8 + ks*32);
#pragma unroll
        for (int u = 0; u < 8; ++u) s[u] += s2f(v[u]);
      }
      af[ks] = (short8){f2s(s[0]),f2s(s[1]),f2s(s[2]),f2s(s[3]),
                        f2s(s[4]),f2s(s[5]),f2s(s[6]),f2s(s[7])};
    }
  }

  const short* Wb = (const short*)WT + ln*128 + qd*8;
  f32x4 acc[8];
#pragma unroll
  for (int ct = 0; ct < 8; ++ct) acc[ct] = (f32x4){0,0,0,0};
#pragma unroll
  for (int ct = 0; ct < 8; ++ct)
#pragma unroll
    for (int ks = 0; ks < 4; ++ks)
      acc[ct] = __builtin_amdgcn_mfma_f32_16x16x32_bf16(af[ks],
                  *(const short8*)(Wb + ct*16*128 + ks*32), acc[ct], 0,0,0);

#pragma unroll
  for (int ct = 0; ct < 8; ++ct) {
    int col = ct*16 + ln;
    float bias = b[col];
#pragma unroll
    for (int reg = 0; reg < 4; ++reg) {
      int crow = row0w + qd*4 + reg;
      size_t o = (size_t)crow*128 + col;
      float v = fmaxf(acc[ct][reg] + bias, 0.f);
      if (resIn) v += resIn[o];
      if (Yf)  Yf[o] = v;
      if (Ybf) Ybf[o] = f2bf(v);
    }
  }
}

// ----------------------------------- pred_cart = segsum(f*unit) per crystal
__global__ void k_pcart(const float* __restrict__ f, const float* __restrict__ unit,
                        const int* __restrict__ dst, float* __restrict__ out) {
  __shared__ float acc[AATOMS * 3];
  int c = blockIdx.x, tid = threadIdx.x;  // 256 threads
  if (tid < AATOMS*3) acc[tid] = 0.f;
  __syncthreads();
  for (int t = tid; t < 1280; t += 256) {
    int e = c*1280 + t;
    int d = dst[e] & 63;
    float fv = f[e];
    atomicAdd(&acc[d*3+0], fv * unit[e*3+0]);
    atomicAdd(&acc[d*3+1], fv * unit[e*3+1]);
    atomicAdd(&acc[d*3+2], fv * unit[e*3+2]);
  }
  __syncthreads();
  if (tid < AATOMS*3) out[c*AATOMS*3 + tid] = acc[tid];
}

// ----------------------------------------- final fc3: (128 -> 2) per atom row
__global__ void k_fc3(const float* __restrict__ a2, const float* __restrict__ W,
                      const float* __restrict__ b, float* __restrict__ out) {
  int lane = threadIdx.x & 63;
  int wave = threadIdx.x >> 6;
  int row = blockIdx.x * 4 + wave;
  float x0 = a2[(size_t)row*HID + lane], x1 = a2[(size_t)row*HID + 64 + lane];
  float p0 = x0 * W[lane*2+0] + x1 * W[(64+lane)*2+0];
  float p1 = x0 * W[lane*2+1] + x1 * W[(64+lane)*2+1];
#pragma unroll
  for (int off = 32; off > 0; off >>= 1) {
    p0 += __shfl_down(p0, off, 64);
    p1 += __shfl_down(p1, off, 64);
  }
  if (lane == 0) {
    out[row*2+0] = p0 + b[0];
    out[row*2+1] = p1 + b[1];
  }
}

extern "C" void kernel_launch(void* const* d_in, const int* in_sizes, int n_in,
                              void* d_out, int out_size, void* d_ws, size_t ws_size,
                              hipStream_t stream) {
  const float* z        = (const float*)d_in[0];
  const float* frac     = (const float*)d_in[1];
  const float* lengths  = (const float*)d_in[2];
  const float* angles   = (const float*)d_in[3];
  const int*   atype    = (const int*)  d_in[4];
  const int*   src      = (const int*)  d_in[5];
  const int*   dst      = (const int*)  d_in[6];
  const float* emb      = (const float*)d_in[7];
  const float* W_in     = (const float*)d_in[8];
  const float* b_in     = (const float*)d_in[9];
  const float* W_edge   = (const float*)d_in[10];
  const float* b_edge   = (const float*)d_in[11];
  const float* Wb_rbf   = (const float*)d_in[12];
  const float* Wb_msg   = (const float*)d_in[13];
  const float* bb_msg   = (const float*)d_in[14];
  const float* Wb_atom  = (const float*)d_in[15];
  const float* bb_atom  = (const float*)d_in[16];
  const float* Wb_upd   = (const float*)d_in[17];
  const float* bb_upd   = (const float*)d_in[18];
  const float* W_force  = (const float*)d_in[19];
  const float* b_force  = (const float*)d_in[20];
  const float* W_fc1    = (const float*)d_in[21];
  const float* b_fc1    = (const float*)d_in[22];
  const float* W_fc2    = (const float*)d_in[23];
  const float* b_fc2    = (const float*)d_in[24];
  const float* W_fc3    = (const float*)d_in[25];
  const float* b_fc3    = (const float*)d_in[26];

  // ---- workspace layout (~150 MB) ----
  char* p = (char*)d_ws;
  float* cart = (float*)p;            p += (size_t)NATOMS*3*4;
  float* unit = (float*)p;            p += (size_t)NEDGE*3*4;       // 3.9 MB
  float* dist = (float*)p;            p += (size_t)NEDGE*4;         // 1.3 MB
  float* h    = (float*)p;            p += (size_t)NATOMS*HID*4;    // 8.4 MB
  float* a2   = (float*)p;            p += (size_t)NATOMS*HID*4;    // 8.4 MB
  float* fbuf = (float*)p;            p += (size_t)NEDGE*4;         // 1.3 MB
  float* T    = (float*)p;            p += (size_t)4*DQ*128*4;      // 8.4 MB
  __hip_bfloat16* h_bf = (__hip_bfloat16*)p; p += (size_t)NATOMS*HID*2;
  __hip_bfloat16* a1bf = (__hip_bfloat16*)p; p += (size_t)NATOMS*HID*2;
  __hip_bfloat16* aggP = (__hip_bfloat16*)p; p += (size_t)NPART*NATOMS*HID*2; // 16.8 MB
  __hip_bfloat16* m    = (__hip_bfloat16*)p; p += (size_t)NEDGE*HID*2;        // 83.9 MB
  __hip_bfloat16* WT   = (__hip_bfloat16*)p; p += (size_t)360448*2;

  __hip_bfloat16* WT_in   = WT;
  __hip_bfloat16* WT_edge = WT + 49152;
  __hip_bfloat16* WT_upd  = WT + 81920;
  __hip_bfloat16* WT_msg  = WT + 229376;
  __hip_bfloat16* WT_atom = WT + 278528;
  __hip_bfloat16* WT_fc1  = WT + 327680;
  __hip_bfloat16* WT_fc2  = WT + 344064;

  float* out_cart = (float*)d_out;
  float* out_at   = out_cart + NATOMS*3;

  k_wcast<<<1408, 256, 0, stream>>>(W_in, W_edge, Wb_upd, Wb_msg, Wb_atom,
                                    W_fc1, W_fc2, WT);
  k_tab<<<DQ, 128, 0, stream>>>(W_edge, Wb_rbf, T);
  k_cart<<<NATOMS/256, 256, 0, stream>>>(frac, lengths, angles, cart);
  k_edge<<<NEDGE/256, 256, 0, stream>>>(cart, src, dst, unit, dist);
  k_hm<<<NATOMS/64, 256, 0, stream>>>(atype, z, emb, WT_in, b_in, h, h_bf);
  k_egemm<256,0><<<NEDGE/128, 256, 0, stream>>>(src, dst, h_bf, nullptr, dist, T,
                                                WT_edge, b_edge, m,
                                                nullptr, nullptr, nullptr);
  for (int i = 0; i < NBLK; ++i) {
    k_msgagg<<<NCRYST*NPART, 512, 0, stream>>>(m, dist, WT_msg + i*16384,
                                               bb_msg + i*HID, T + (size_t)(1+i)*DQ*128,
                                               dst, aggP);
    k_fcm<<<NATOMS/64, 256, 0, stream>>>(nullptr, aggP, NPART, WT_atom + i*16384,
                                         bb_atom + i*HID, h, h, h_bf);
    if (i < NBLK-1) {
      k_egemm<384,1><<<NEDGE/128, 256, 0, stream>>>(src, dst, h_bf, m, nullptr, nullptr,
                                                    WT_upd + i*49152, bb_upd + i*HID, m,
                                                    nullptr, nullptr, nullptr);
    } else {
      k_egemm<384,2><<<NEDGE/128, 256, 0, stream>>>(src, dst, h_bf, m, nullptr, nullptr,
                                                    WT_upd + i*49152, bb_upd + i*HID,
                                                    nullptr, W_force, b_force, fbuf);
    }
  }
  k_pcart<<<NCRYST, 256, 0, stream>>>(fbuf, unit, dst, out_cart);
  k_fcm<<<NATOMS/64, 256, 0, stream>>>(h_bf, nullptr, 1, WT_fc1, b_fc1,
                                       nullptr, nullptr, a1bf);
  k_fcm<<<NATOMS/64, 256, 0, stream>>>(a1bf, nullptr, 1, WT_fc2, b_fc2,
                                       nullptr, a2, nullptr);
  k_fc3<<<NATOMS/4, 256, 0, stream>>>(a2, W_fc3, b_fc3, out_at);
}

// Round 9
// 1369.691 us; speedup vs baseline: 1.4323x; 1.0865x over previous
//
#include <hip/hip_runtime.h>
#include <hip/hip_bf16.h>

#define NCRYST 256
#define AATOMS 64
#define KNBR   20
#define HID    128
#define LAT    256
#define NRBF   128
#define NBLK   3
#define NATOMS (NCRYST * AATOMS)   // 16384
#define NEDGE  (NATOMS * KNBR)     // 327680
#define NPART  4                   // agg partial slices per crystal
#define DQ     4096                // dist-table knots over [0, CUT]
#define PI_F   3.14159265358979323846f
#define CUT_F  6.0f

typedef short short8 __attribute__((ext_vector_type(8)));   // 8 bf16 (4 VGPRs)
typedef float f32x4  __attribute__((ext_vector_type(4)));   // MFMA C/D

__device__ __forceinline__ float bf2f(__hip_bfloat16 x) { return __bfloat162float(x); }
__device__ __forceinline__ __hip_bfloat16 f2bf(float x) { return __float2bfloat16(x); }
__device__ __forceinline__ float s2f(short x) {
  return __uint_as_float(((unsigned)(unsigned short)x) << 16);
}
__device__ __forceinline__ short f2s(float x) {
  union { short s; __hip_bfloat16 b; } u; u.b = f2bf(x); return u.s;
}

// lerp lookup in a [DQ][128] f32 table; exact 0 for d >= CUT (matches env==0)
__device__ __forceinline__ float tlook(const float* __restrict__ T, float d, int col) {
  if (d >= CUT_F) return 0.f;
  float x = d * ((float)(DQ - 1) / CUT_F);
  int i0 = (int)x;
  float fr = x - (float)i0;
  float v0 = T[i0 * 128 + col];
  float v1 = T[(i0 + 1) * 128 + col];
  return fmaf(fr, v1 - v0, v0);
}

// ---------------------------------------------------------------- cart coords
__global__ void k_cart(const float* __restrict__ frac, const float* __restrict__ lengths,
                       const float* __restrict__ angles, float* __restrict__ cart) {
  int atom = blockIdx.x * blockDim.x + threadIdx.x;
  if (atom >= NATOMS) return;
  int c = atom >> 6;
  float al = angles[c*3+0] * (PI_F/180.f);
  float be = angles[c*3+1] * (PI_F/180.f);
  float ga = angles[c*3+2] * (PI_F/180.f);
  float ca = cosf(al), cb = cosf(be), cg = cosf(ga), sg = sinf(ga);
  float a = lengths[c*3+0], b = lengths[c*3+1], cl = lengths[c*3+2];
  float cx = cl * cb;
  float cy = cl * (ca - cb*cg) / sg;
  float cz = sqrtf(fmaxf(cl*cl - cx*cx - cy*cy, 1e-8f));
  float f0 = frac[atom*3+0], f1 = frac[atom*3+1], f2 = frac[atom*3+2];
  cart[atom*3+0] = f0*a + f1*(b*cg) + f2*cx;
  cart[atom*3+1] = f1*(b*sg) + f2*cy;
  cart[atom*3+2] = f2*cz;
}

// ---------------- edge geometry: unit + dist; also init fbuf[e] = b_force
__global__ void k_edge(const float* __restrict__ cart, const int* __restrict__ src,
                       const int* __restrict__ dst, float* __restrict__ unit,
                       float* __restrict__ dist, const float* __restrict__ b_force,
                       float* __restrict__ fbuf) {
  int e = blockIdx.x * blockDim.x + threadIdx.x;
  if (e >= NEDGE) return;
  int s = src[e], d = dst[e];
  float dx = cart[d*3+0] - cart[s*3+0];
  float dy = cart[d*3+1] - cart[s*3+1];
  float dz = cart[d*3+2] - cart[s*3+2];
  float dd = sqrtf(dx*dx + dy*dy + dz*dz + 1e-12f);
  float inv = 1.f / dd;
  dist[e] = dd;
  unit[e*3+0] = dx*inv; unit[e*3+1] = dy*inv; unit[e*3+2] = dz*inv;
  fbuf[e] = b_force[0];
}

// ---------------- dist tables: T[0]=rbf@W_edge[256:384], T[1+i]=rbf@Wb_rbf[i]
__global__ __launch_bounds__(128) void k_tab(const float* __restrict__ W_edge,
                                             const float* __restrict__ Wb_rbf,
                                             float* __restrict__ T) {
  int q = blockIdx.x, n = threadIdx.x;
  __shared__ float rv[128];
  float d = (float)q * (CUT_F / (float)(DQ - 1));
  float env = 0.5f * (cosf(PI_F * fminf(d * (1.f/CUT_F), 1.f)) + 1.f);
  float t = (d - (float)n * (CUT_F/(NRBF-1))) * ((NRBF-1)/CUT_F);
  rv[n] = expf(-t*t) * env;
  __syncthreads();
  float a0 = 0.f, a1 = 0.f, a2 = 0.f, a3 = 0.f;
  for (int j = 0; j < 128; ++j) {
    float r = rv[j];
    a0 = fmaf(r, W_edge[(256 + j)*128 + n], a0);
    a1 = fmaf(r, Wb_rbf[0*16384 + j*128 + n], a1);
    a2 = fmaf(r, Wb_rbf[1*16384 + j*128 + n], a2);
    a3 = fmaf(r, Wb_rbf[2*16384 + j*128 + n], a3);
  }
  T[(0*DQ + q)*128 + n] = a0;
  T[(1*DQ + q)*128 + n] = a1;
  T[(2*DQ + q)*128 + n] = a2;
  T[(3*DQ + q)*128 + n] = a3;
}

// ----------------- weights: transpose + cast to bf16 (n-major)
__global__ void k_wcast(const float* __restrict__ W_in, const float* __restrict__ W_edge,
                        const float* __restrict__ Wb_upd, const float* __restrict__ Wb_msg,
                        const float* __restrict__ Wb_atom, const float* __restrict__ W_fc1,
                        const float* __restrict__ W_fc2, __hip_bfloat16* __restrict__ WT) {
  int idx = blockIdx.x * 256 + threadIdx.x;
  if (idx >= 360448) return;
  int t = idx; const float* S; int K;
  if (t < 49152)                { S = W_in;  K = 384; }
  else if ((t -= 49152) < 32768)  { S = W_edge; K = 256; }
  else if ((t -= 32768) < 147456) { S = Wb_upd + (t/49152)*49152; t %= 49152; K = 384; }
  else if ((t -= 147456) < 49152) { S = Wb_msg + (t/16384)*16384; t %= 16384; K = 128; }
  else if ((t -= 49152) < 49152)  { S = Wb_atom + (t/16384)*16384; t %= 16384; K = 128; }
  else if ((t -= 49152) < 16384)  { S = W_fc1; K = 128; }
  else                            { t -= 16384; S = W_fc2; K = 128; }
  int n = t / K, k = t % K;
  WT[idx] = f2bf(S[k*128 + n]);
}

// ============ MFMA h: h = relu([emb[atype]|z]@W_in + b), 64 rows/block
__global__ __launch_bounds__(256) void k_hm(
    const int* __restrict__ atype, const float* __restrict__ z,
    const float* __restrict__ emb, const __hip_bfloat16* __restrict__ WTin,
    const float* __restrict__ b, float* __restrict__ h,
    __hip_bfloat16* __restrict__ h_bf) {
  const int tid = threadIdx.x;
  const int w = tid >> 6, lane = tid & 63, ln = lane & 15, qd = lane >> 4;
  const int row0w = blockIdx.x * 64 + w * 16;
  const int arow = row0w + ln;
  const float* esrc = emb + (size_t)atype[arow] * 128;
  const float* zsrc = z + (size_t)(arow >> 6) * LAT;

  short8 af[12];
#pragma unroll
  for (int ks = 0; ks < 4; ++ks) {
    float4 v0 = *(const float4*)(esrc + ks*32 + qd*8);
    float4 v1 = *(const float4*)(esrc + ks*32 + qd*8 + 4);
    af[ks] = (short8){f2s(v0.x),f2s(v0.y),f2s(v0.z),f2s(v0.w),
                      f2s(v1.x),f2s(v1.y),f2s(v1.z),f2s(v1.w)};
  }
#pragma unroll
  for (int ks = 4; ks < 12; ++ks) {
    float4 v0 = *(const float4*)(zsrc + (ks-4)*32 + qd*8);
    float4 v1 = *(const float4*)(zsrc + (ks-4)*32 + qd*8 + 4);
    af[ks] = (short8){f2s(v0.x),f2s(v0.y),f2s(v0.z),f2s(v0.w),
                      f2s(v1.x),f2s(v1.y),f2s(v1.z),f2s(v1.w)};
  }

  const short* Wb = (const short*)WTin + ln*384 + qd*8;
  f32x4 acc[8];
#pragma unroll
  for (int ct = 0; ct < 8; ++ct) acc[ct] = (f32x4){0,0,0,0};
#pragma unroll
  for (int ks = 0; ks < 12; ++ks)
#pragma unroll
    for (int ct = 0; ct < 8; ++ct)
      acc[ct] = __builtin_amdgcn_mfma_f32_16x16x32_bf16(af[ks],
                  *(const short8*)(Wb + ct*16*384 + ks*32), acc[ct], 0,0,0);

#pragma unroll
  for (int ct = 0; ct < 8; ++ct) {
    int col = ct*16 + ln;
    float bias = b[col];
#pragma unroll
    for (int reg = 0; reg < 4; ++reg) {
      int crow = row0w + qd*4 + reg;
      float v = fmaxf(acc[ct][reg] + bias, 0.f);
      size_t o = (size_t)crow*128 + col;
      h[o] = v;
      h_bf[o] = f2bf(v);
    }
  }
}

// ============ MFMA edge GEMM v2: wave = 32 rows x 64 cols; A loaded UPFRONT.
// block = 256 thr: rh = w>>1 picks 32-row half, cg = w&1 picks 64-col half.
// MODE 0: out = bf16(relu(hs@W1 + hd@W2 + T0(d) + b))         (KD=256)
// MODE 1: out = bf16(m + relu([hs|hd|m]@W + b))               (KD=384)
// MODE 2: MODE1 value v, NO m store; atomicAdd(fout[row], sum_col v*Wf)
template<int KD, int MODE>
__global__ __launch_bounds__(256) void k_egemm(
    const int* __restrict__ src, const int* __restrict__ dst,
    const __hip_bfloat16* __restrict__ h_bf,
    const __hip_bfloat16* __restrict__ m_in,
    const float* __restrict__ dist, const float* __restrict__ T0,
    const __hip_bfloat16* __restrict__ WT, const float* __restrict__ b,
    __hip_bfloat16* __restrict__ out,
    const float* __restrict__ Wf, float* __restrict__ fout) {
  const int tid = threadIdx.x;
  const int w = tid >> 6, lane = tid & 63, ln = lane & 15, qd = lane >> 4;
  const int cg = w & 1, rh = w >> 1;
  const int row0 = blockIdx.x * 64 + rh * 32;
  constexpr int NSEG = KD / 32;

  const int r_a = row0 + ln, r_b = row0 + 16 + ln;

  // ---- phase 1: issue ALL A-fragment loads (independent, stay in flight) ----
  short8 afA[NSEG], afB[NSEG];
  {
    const short* hsA = (const short*)h_bf + (size_t)src[r_a]*HID + qd*8;
    const short* hdA = (const short*)h_bf + (size_t)dst[r_a]*HID + qd*8;
    const short* hsB = (const short*)h_bf + (size_t)src[r_b]*HID + qd*8;
    const short* hdB = (const short*)h_bf + (size_t)dst[r_b]*HID + qd*8;
#pragma unroll
    for (int k2 = 0; k2 < 4; ++k2) {
      afA[k2]   = *(const short8*)(hsA + k2*32);
      afB[k2]   = *(const short8*)(hsB + k2*32);
      afA[4+k2] = *(const short8*)(hdA + k2*32);
      afB[4+k2] = *(const short8*)(hdB + k2*32);
    }
    if constexpr (MODE >= 1) {
      const short* thA = (const short*)m_in + (size_t)r_a*HID + qd*8;
      const short* thB = (const short*)m_in + (size_t)r_b*HID + qd*8;
#pragma unroll
      for (int k2 = 0; k2 < 4; ++k2) {
        afA[8+k2] = *(const short8*)(thA + k2*32);
        afB[8+k2] = *(const short8*)(thB + k2*32);
      }
    }
  }

  // ---- phase 2: B loop (L2-resident weights) + MFMAs ----
  f32x4 acc0[4], acc1[4];
#pragma unroll
  for (int ct = 0; ct < 4; ++ct) { acc0[ct] = (f32x4){0,0,0,0}; acc1[ct] = (f32x4){0,0,0,0}; }

#pragma unroll
  for (int ks = 0; ks < NSEG; ++ks) {
#pragma unroll
    for (int ct = 0; ct < 4; ++ct) {
      const short* bbp = (const short*)WT + (size_t)(cg*64 + ct*16 + ln)*KD + qd*8 + ks*32;
      short8 bb = *(const short8*)bbp;
      acc0[ct] = __builtin_amdgcn_mfma_f32_16x16x32_bf16(afA[ks], bb, acc0[ct], 0,0,0);
      acc1[ct] = __builtin_amdgcn_mfma_f32_16x16x32_bf16(afB[ks], bb, acc1[ct], 0,0,0);
    }
  }

  // ---- epilogue ----
  float bias4[4], wf4[4];
#pragma unroll
  for (int ct = 0; ct < 4; ++ct) bias4[ct] = b[cg*64 + ct*16 + ln];
  if constexpr (MODE == 2) {
#pragma unroll
    for (int ct = 0; ct < 4; ++ct) wf4[ct] = Wf[cg*64 + ct*16 + ln];
  }

#pragma unroll
  for (int mt = 0; mt < 2; ++mt) {
    const f32x4* acc = mt ? acc1 : acc0;
#pragma unroll
    for (int reg = 0; reg < 4; ++reg) {
      int row = row0 + mt*16 + qd*4 + reg;
      float dr = 0.f;
      if constexpr (MODE == 0) dr = dist[row];
      float fp = 0.f;
#pragma unroll
      for (int ct = 0; ct < 4; ++ct) {
        int col = cg*64 + ct*16 + ln;
        float v;
        if constexpr (MODE == 0) {
          v = fmaxf(acc[ct][reg] + bias4[ct] + tlook(T0, dr, col), 0.f);
        } else {
          v = fmaxf(acc[ct][reg] + bias4[ct], 0.f)
              + bf2f(m_in[(size_t)row*HID + col]);
        }
        if constexpr (MODE != 2) out[(size_t)row*HID + col] = f2bf(v);
        if constexpr (MODE == 2) fp = fmaf(v, wf4[ct], fp);
      }
      if constexpr (MODE == 2) {
        fp += __shfl_xor(fp, 1, 64);
        fp += __shfl_xor(fp, 2, 64);
        fp += __shfl_xor(fp, 4, 64);
        fp += __shfl_xor(fp, 8, 64);
        if (ln == 0) atomicAdd(&fout[row], fp);   // fbuf pre-init to b_force
      }
    }
  }
}

// ===== fused msg+segsum, NPART partial blocks per crystal -> bf16 aggP slices
// msg = relu(m@Wm+bm) * gate(d); all tile A-frags prefetched upfront.
__global__ __launch_bounds__(512) void k_msgagg(
    const __hip_bfloat16* __restrict__ m, const float* __restrict__ dist,
    const __hip_bfloat16* __restrict__ WmT, const float* __restrict__ bm,
    const float* __restrict__ Tg, const int* __restrict__ dst,
    __hip_bfloat16* __restrict__ aggP) {
  __shared__ float agg[64 * 132];
  const int tid = threadIdx.x;
  const int c = blockIdx.x & 255, pq = blockIdx.x >> 8;
  const int w = tid >> 6, lane = tid & 63, ln = lane & 15, qd = lane >> 4;

  for (int i = tid; i < 64*132; i += 512) agg[i] = 0.f;
  float bias8[8];
#pragma unroll
  for (int ct = 0; ct < 8; ++ct) bias8[ct] = bm[ct*16 + ln];

  // prefetch ALL tiles for this wave (s = w, w+8, w+16 while < 20)
  const int nt = (w < 4) ? 3 : 2;
  int e0s[3]; short8 am[3][4]; int d4[3][4]; float dd4[3][4];
#pragma unroll
  for (int t = 0; t < 3; ++t) {
    if (t < nt) {
      int e0 = c * 1280 + pq * 320 + (w + t*8) * 16;
      e0s[t] = e0;
      const short* pm = (const short*)m + (size_t)(e0 + ln)*HID + qd*8;
#pragma unroll
      for (int ks = 0; ks < 4; ++ks) am[t][ks] = *(const short8*)(pm + ks*32);
#pragma unroll
      for (int reg = 0; reg < 4; ++reg) {
        d4[t][reg]  = dst[e0 + qd*4 + reg] & 63;
        dd4[t][reg] = dist[e0 + qd*4 + reg];
      }
    }
  }
  __syncthreads();

  for (int t = 0; t < nt; ++t) {
    f32x4 accM[8];
#pragma unroll
    for (int ct = 0; ct < 8; ++ct) accM[ct] = (f32x4){0,0,0,0};
#pragma unroll
    for (int ct = 0; ct < 8; ++ct) {
      const short* bmp = (const short*)WmT + (ct*16 + ln)*128 + qd*8;
#pragma unroll
      for (int ks = 0; ks < 4; ++ks)
        accM[ct] = __builtin_amdgcn_mfma_f32_16x16x32_bf16(am[t][ks],
                     *(const short8*)(bmp + ks*32), accM[ct], 0,0,0);
    }
#pragma unroll
    for (int ct = 0; ct < 8; ++ct) {
      int col = ct*16 + ln;
#pragma unroll
      for (int reg = 0; reg < 4; ++reg) {
        float g = tlook(Tg, dd4[t][reg], col);
        float v = fmaxf(accM[ct][reg] + bias8[ct], 0.f) * g;
        if (v != 0.f) atomicAdd(&agg[d4[t][reg]*132 + col], v);
      }
    }
  }
  __syncthreads();
  __hip_bfloat16* outp = aggP + ((size_t)pq * NATOMS + c * 64) * HID;
  for (int i = tid; i < 64*128; i += 512) {
    int a = i >> 7, col = i & 127;
    outp[a*HID + col] = f2bf(agg[a*132 + col]);
  }
}

// ============ MFMA fc (K=128): Y = [res +] relu(A@W + b)
__global__ __launch_bounds__(256) void k_fcm(
    const __hip_bfloat16* __restrict__ A,       // nslice==1
    const __hip_bfloat16* __restrict__ slices,  // nslice==NPART
    int nslice,
    const __hip_bfloat16* __restrict__ WT, const float* __restrict__ b,
    const float* __restrict__ resIn,            // nullable
    float* __restrict__ Yf,                     // nullable
    __hip_bfloat16* __restrict__ Ybf) {         // nullable
  const int tid = threadIdx.x;
  const int w = tid >> 6, lane = tid & 63, ln = lane & 15, qd = lane >> 4;
  const int row0w = blockIdx.x * 64 + w * 16;
  const int arow = row0w + ln;

  short8 af[4];
  if (nslice == 1) {
    const short* pa = (const short*)A + (size_t)arow*128 + qd*8;
#pragma unroll
    for (int ks = 0; ks < 4; ++ks) af[ks] = *(const short8*)(pa + ks*32);
  } else {
#pragma unroll
    for (int ks = 0; ks < 4; ++ks) {
      float s[8] = {0,0,0,0,0,0,0,0};
#pragma unroll
      for (int p = 0; p < NPART; ++p) {
        short8 v = *(const short8*)((const short*)slices +
                     (size_t)p*NATOMS*128 + (size_t)arow*128 + qd*8 + ks*32);
#pragma unroll
        for (int u = 0; u < 8; ++u) s[u] += s2f(v[u]);
      }
      af[ks] = (short8){f2s(s[0]),f2s(s[1]),f2s(s[2]),f2s(s[3]),
                        f2s(s[4]),f2s(s[5]),f2s(s[6]),f2s(s[7])};
    }
  }

  const short* Wb = (const short*)WT + ln*128 + qd*8;
  f32x4 acc[8];
#pragma unroll
  for (int ct = 0; ct < 8; ++ct) acc[ct] = (f32x4){0,0,0,0};
#pragma unroll
  for (int ct = 0; ct < 8; ++ct)
#pragma unroll
    for (int ks = 0; ks < 4; ++ks)
      acc[ct] = __builtin_amdgcn_mfma_f32_16x16x32_bf16(af[ks],
                  *(const short8*)(Wb + ct*16*128 + ks*32), acc[ct], 0,0,0);

#pragma unroll
  for (int ct = 0; ct < 8; ++ct) {
    int col = ct*16 + ln;
    float bias = b[col];
#pragma unroll
    for (int reg = 0; reg < 4; ++reg) {
      int crow = row0w + qd*4 + reg;
      size_t o = (size_t)crow*128 + col;
      float v = fmaxf(acc[ct][reg] + bias, 0.f);
      if (resIn) v += resIn[o];
      if (Yf)  Yf[o] = v;
      if (Ybf) Ybf[o] = f2bf(v);
    }
  }
}

// ----------------------------------- pred_cart = segsum(f*unit) per crystal
__global__ void k_pcart(const float* __restrict__ f, const float* __restrict__ unit,
                        const int* __restrict__ dst, float* __restrict__ out) {
  __shared__ float acc[AATOMS * 3];
  int c = blockIdx.x, tid = threadIdx.x;  // 256 threads
  if (tid < AATOMS*3) acc[tid] = 0.f;
  __syncthreads();
  for (int t = tid; t < 1280; t += 256) {
    int e = c*1280 + t;
    int d = dst[e] & 63;
    float fv = f[e];
    atomicAdd(&acc[d*3+0], fv * unit[e*3+0]);
    atomicAdd(&acc[d*3+1], fv * unit[e*3+1]);
    atomicAdd(&acc[d*3+2], fv * unit[e*3+2]);
  }
  __syncthreads();
  if (tid < AATOMS*3) out[c*AATOMS*3 + tid] = acc[tid];
}

// ----------------------------------------- final fc3: (128 -> 2) per atom row
__global__ void k_fc3(const float* __restrict__ a2, const float* __restrict__ W,
                      const float* __restrict__ b, float* __restrict__ out) {
  int lane = threadIdx.x & 63;
  int wave = threadIdx.x >> 6;
  int row = blockIdx.x * 4 + wave;
  float x0 = a2[(size_t)row*HID + lane], x1 = a2[(size_t)row*HID + 64 + lane];
  float p0 = x0 * W[lane*2+0] + x1 * W[(64+lane)*2+0];
  float p1 = x0 * W[lane*2+1] + x1 * W[(64+lane)*2+1];
#pragma unroll
  for (int off = 32; off > 0; off >>= 1) {
    p0 += __shfl_down(p0, off, 64);
    p1 += __shfl_down(p1, off, 64);
  }
  if (lane == 0) {
    out[row*2+0] = p0 + b[0];
    out[row*2+1] = p1 + b[1];
  }
}

extern "C" void kernel_launch(void* const* d_in, const int* in_sizes, int n_in,
                              void* d_out, int out_size, void* d_ws, size_t ws_size,
                              hipStream_t stream) {
  const float* z        = (const float*)d_in[0];
  const float* frac     = (const float*)d_in[1];
  const float* lengths  = (const float*)d_in[2];
  const float* angles   = (const float*)d_in[3];
  const int*   atype    = (const int*)  d_in[4];
  const int*   src      = (const int*)  d_in[5];
  const int*   dst      = (const int*)  d_in[6];
  const float* emb      = (const float*)d_in[7];
  const float* W_in     = (const float*)d_in[8];
  const float* b_in     = (const float*)d_in[9];
  const float* W_edge   = (const float*)d_in[10];
  const float* b_edge   = (const float*)d_in[11];
  const float* Wb_rbf   = (const float*)d_in[12];
  const float* Wb_msg   = (const float*)d_in[13];
  const float* bb_msg   = (const float*)d_in[14];
  const float* Wb_atom  = (const float*)d_in[15];
  const float* bb_atom  = (const float*)d_in[16];
  const float* Wb_upd   = (const float*)d_in[17];
  const float* bb_upd   = (const float*)d_in[18];
  const float* W_force  = (const float*)d_in[19];
  const float* b_force  = (const float*)d_in[20];
  const float* W_fc1    = (const float*)d_in[21];
  const float* b_fc1    = (const float*)d_in[22];
  const float* W_fc2    = (const float*)d_in[23];
  const float* b_fc2    = (const float*)d_in[24];
  const float* W_fc3    = (const float*)d_in[25];
  const float* b_fc3    = (const float*)d_in[26];

  // ---- workspace layout (~150 MB) ----
  char* p = (char*)d_ws;
  float* cart = (float*)p;            p += (size_t)NATOMS*3*4;
  float* unit = (float*)p;            p += (size_t)NEDGE*3*4;       // 3.9 MB
  float* dist = (float*)p;            p += (size_t)NEDGE*4;         // 1.3 MB
  float* h    = (float*)p;            p += (size_t)NATOMS*HID*4;    // 8.4 MB
  float* a2   = (float*)p;            p += (size_t)NATOMS*HID*4;    // 8.4 MB
  float* fbuf = (float*)p;            p += (size_t)NEDGE*4;         // 1.3 MB
  float* T    = (float*)p;            p += (size_t)4*DQ*128*4;      // 8.4 MB
  __hip_bfloat16* h_bf = (__hip_bfloat16*)p; p += (size_t)NATOMS*HID*2;
  __hip_bfloat16* a1bf = (__hip_bfloat16*)p; p += (size_t)NATOMS*HID*2;
  __hip_bfloat16* aggP = (__hip_bfloat16*)p; p += (size_t)NPART*NATOMS*HID*2; // 16.8 MB
  __hip_bfloat16* m    = (__hip_bfloat16*)p; p += (size_t)NEDGE*HID*2;        // 83.9 MB
  __hip_bfloat16* WT   = (__hip_bfloat16*)p; p += (size_t)360448*2;

  __hip_bfloat16* WT_in   = WT;
  __hip_bfloat16* WT_edge = WT + 49152;
  __hip_bfloat16* WT_upd  = WT + 81920;
  __hip_bfloat16* WT_msg  = WT + 229376;
  __hip_bfloat16* WT_atom = WT + 278528;
  __hip_bfloat16* WT_fc1  = WT + 327680;
  __hip_bfloat16* WT_fc2  = WT + 344064;

  float* out_cart = (float*)d_out;
  float* out_at   = out_cart + NATOMS*3;

  k_wcast<<<1408, 256, 0, stream>>>(W_in, W_edge, Wb_upd, Wb_msg, Wb_atom,
                                    W_fc1, W_fc2, WT);
  k_tab<<<DQ, 128, 0, stream>>>(W_edge, Wb_rbf, T);
  k_cart<<<NATOMS/256, 256, 0, stream>>>(frac, lengths, angles, cart);
  k_edge<<<NEDGE/256, 256, 0, stream>>>(cart, src, dst, unit, dist, b_force, fbuf);
  k_hm<<<NATOMS/64, 256, 0, stream>>>(atype, z, emb, WT_in, b_in, h, h_bf);
  k_egemm<256,0><<<NEDGE/64, 256, 0, stream>>>(src, dst, h_bf, nullptr, dist, T,
                                               WT_edge, b_edge, m, nullptr, nullptr);
  for (int i = 0; i < NBLK; ++i) {
    k_msgagg<<<NCRYST*NPART, 512, 0, stream>>>(m, dist, WT_msg + i*16384,
                                               bb_msg + i*HID, T + (size_t)(1+i)*DQ*128,
                                               dst, aggP);
    k_fcm<<<NATOMS/64, 256, 0, stream>>>(nullptr, aggP, NPART, WT_atom + i*16384,
                                         bb_atom + i*HID, h, h, h_bf);
    if (i < NBLK-1) {
      k_egemm<384,1><<<NEDGE/64, 256, 0, stream>>>(src, dst, h_bf, m, nullptr, nullptr,
                                                   WT_upd + i*49152, bb_upd + i*HID, m,
                                                   nullptr, nullptr);
    } else {
      k_egemm<384,2><<<NEDGE/64, 256, 0, stream>>>(src, dst, h_bf, m, nullptr, nullptr,
                                                   WT_upd + i*49152, bb_upd + i*HID,
                                                   nullptr, W_force, fbuf);
    }
  }
  k_pcart<<<NCRYST, 256, 0, stream>>>(fbuf, unit, dst, out_cart);
  k_fcm<<<NATOMS/64, 256, 0, stream>>>(h_bf, nullptr, 1, WT_fc1, b_fc1,
                                       nullptr, nullptr, a1bf);
  k_fcm<<<NATOMS/64, 256, 0, stream>>>(a1bf, nullptr, 1, WT_fc2, b_fc2,
                                       nullptr, a2, nullptr);
  k_fc3<<<NATOMS/4, 256, 0, stream>>>(a2, W_fc3, b_fc3, out_at);
}

// Round 10
// 1271.015 us; speedup vs baseline: 1.5435x; 1.0776x over previous
//
#include <hip/hip_runtime.h>
#include <hip/hip_bf16.h>

#define NCRYST 256
#define AATOMS 64
#define KNBR   20
#define HID    128
#define LAT    256
#define NRBF   128
#define NBLK   3
#define NATOMS (NCRYST * AATOMS)   // 16384
#define NEDGE  (NATOMS * KNBR)     // 327680
#define NPART  8                   // agg partial slices per crystal
#define DQ     4096                // dist-table knots over [0, CUT]
#define PI_F   3.14159265358979323846f
#define CUT_F  6.0f

typedef short short8 __attribute__((ext_vector_type(8)));   // 8 bf16 (4 VGPRs)
typedef float f32x4  __attribute__((ext_vector_type(4)));   // MFMA C/D

__device__ __forceinline__ float bf2f(__hip_bfloat16 x) { return __bfloat162float(x); }
__device__ __forceinline__ __hip_bfloat16 f2bf(float x) { return __float2bfloat16(x); }
__device__ __forceinline__ float s2f(short x) {
  return __uint_as_float(((unsigned)(unsigned short)x) << 16);
}
__device__ __forceinline__ short f2s(float x) {
  union { short s; __hip_bfloat16 b; } u; u.b = f2bf(x); return u.s;
}

// lerp lookup in a [DQ][128] f32 table; exact 0 for d >= CUT (matches env==0)
__device__ __forceinline__ float tlook(const float* __restrict__ T, float d, int col) {
  if (d >= CUT_F) return 0.f;
  float x = d * ((float)(DQ - 1) / CUT_F);
  int i0 = (int)x;
  float fr = x - (float)i0;
  float v0 = T[i0 * 128 + col];
  float v1 = T[(i0 + 1) * 128 + col];
  return fmaf(fr, v1 - v0, v0);
}

// ---------------------------------------------------------------- cart coords
__global__ void k_cart(const float* __restrict__ frac, const float* __restrict__ lengths,
                       const float* __restrict__ angles, float* __restrict__ cart) {
  int atom = blockIdx.x * blockDim.x + threadIdx.x;
  if (atom >= NATOMS) return;
  int c = atom >> 6;
  float al = angles[c*3+0] * (PI_F/180.f);
  float be = angles[c*3+1] * (PI_F/180.f);
  float ga = angles[c*3+2] * (PI_F/180.f);
  float ca = cosf(al), cb = cosf(be), cg = cosf(ga), sg = sinf(ga);
  float a = lengths[c*3+0], b = lengths[c*3+1], cl = lengths[c*3+2];
  float cx = cl * cb;
  float cy = cl * (ca - cb*cg) / sg;
  float cz = sqrtf(fmaxf(cl*cl - cx*cx - cy*cy, 1e-8f));
  float f0 = frac[atom*3+0], f1 = frac[atom*3+1], f2 = frac[atom*3+2];
  cart[atom*3+0] = f0*a + f1*(b*cg) + f2*cx;
  cart[atom*3+1] = f1*(b*sg) + f2*cy;
  cart[atom*3+2] = f2*cz;
}

// ---------------- edge geometry: unit + dist; also init fbuf[e] = b_force
__global__ void k_edge(const float* __restrict__ cart, const int* __restrict__ src,
                       const int* __restrict__ dst, float* __restrict__ unit,
                       float* __restrict__ dist, const float* __restrict__ b_force,
                       float* __restrict__ fbuf) {
  int e = blockIdx.x * blockDim.x + threadIdx.x;
  if (e >= NEDGE) return;
  int s = src[e], d = dst[e];
  float dx = cart[d*3+0] - cart[s*3+0];
  float dy = cart[d*3+1] - cart[s*3+1];
  float dz = cart[d*3+2] - cart[s*3+2];
  float dd = sqrtf(dx*dx + dy*dy + dz*dz + 1e-12f);
  float inv = 1.f / dd;
  dist[e] = dd;
  unit[e*3+0] = dx*inv; unit[e*3+1] = dy*inv; unit[e*3+2] = dz*inv;
  fbuf[e] = b_force[0];
}

// ---------------- dist tables: T[0]=rbf@W_edge[256:384], T[1+i]=rbf@Wb_rbf[i]
__global__ __launch_bounds__(128) void k_tab(const float* __restrict__ W_edge,
                                             const float* __restrict__ Wb_rbf,
                                             float* __restrict__ T) {
  int q = blockIdx.x, n = threadIdx.x;
  __shared__ float rv[128];
  float d = (float)q * (CUT_F / (float)(DQ - 1));
  float env = 0.5f * (cosf(PI_F * fminf(d * (1.f/CUT_F), 1.f)) + 1.f);
  float t = (d - (float)n * (CUT_F/(NRBF-1))) * ((NRBF-1)/CUT_F);
  rv[n] = expf(-t*t) * env;
  __syncthreads();
  float a0 = 0.f, a1 = 0.f, a2 = 0.f, a3 = 0.f;
  for (int j = 0; j < 128; ++j) {
    float r = rv[j];
    a0 = fmaf(r, W_edge[(256 + j)*128 + n], a0);
    a1 = fmaf(r, Wb_rbf[0*16384 + j*128 + n], a1);
    a2 = fmaf(r, Wb_rbf[1*16384 + j*128 + n], a2);
    a3 = fmaf(r, Wb_rbf[2*16384 + j*128 + n], a3);
  }
  T[(0*DQ + q)*128 + n] = a0;
  T[(1*DQ + q)*128 + n] = a1;
  T[(2*DQ + q)*128 + n] = a2;
  T[(3*DQ + q)*128 + n] = a3;
}

// ----------------- weights: transpose + cast to bf16 (n-major)
__global__ void k_wcast(const float* __restrict__ W_in, const float* __restrict__ W_edge,
                        const float* __restrict__ Wb_upd, const float* __restrict__ Wb_msg,
                        const float* __restrict__ Wb_atom, const float* __restrict__ W_fc1,
                        const float* __restrict__ W_fc2, __hip_bfloat16* __restrict__ WT) {
  int idx = blockIdx.x * 256 + threadIdx.x;
  if (idx >= 360448) return;
  int t = idx; const float* S; int K;
  if (t < 49152)                { S = W_in;  K = 384; }
  else if ((t -= 49152) < 32768)  { S = W_edge; K = 256; }
  else if ((t -= 32768) < 147456) { S = Wb_upd + (t/49152)*49152; t %= 49152; K = 384; }
  else if ((t -= 147456) < 49152) { S = Wb_msg + (t/16384)*16384; t %= 16384; K = 128; }
  else if ((t -= 49152) < 49152)  { S = Wb_atom + (t/16384)*16384; t %= 16384; K = 128; }
  else if ((t -= 49152) < 16384)  { S = W_fc1; K = 128; }
  else                            { t -= 16384; S = W_fc2; K = 128; }
  int n = t / K, k = t % K;
  WT[idx] = f2bf(S[k*128 + n]);
}

// ============ MFMA h: h = relu([emb[atype]|z]@W_in + b), 64 rows/block
__global__ __launch_bounds__(256) void k_hm(
    const int* __restrict__ atype, const float* __restrict__ z,
    const float* __restrict__ emb, const __hip_bfloat16* __restrict__ WTin,
    const float* __restrict__ b, float* __restrict__ h,
    __hip_bfloat16* __restrict__ h_bf) {
  const int tid = threadIdx.x;
  const int w = tid >> 6, lane = tid & 63, ln = lane & 15, qd = lane >> 4;
  const int row0w = blockIdx.x * 64 + w * 16;
  const int arow = row0w + ln;
  const float* esrc = emb + (size_t)atype[arow] * 128;
  const float* zsrc = z + (size_t)(arow >> 6) * LAT;

  short8 af[12];
#pragma unroll
  for (int ks = 0; ks < 4; ++ks) {
    float4 v0 = *(const float4*)(esrc + ks*32 + qd*8);
    float4 v1 = *(const float4*)(esrc + ks*32 + qd*8 + 4);
    af[ks] = (short8){f2s(v0.x),f2s(v0.y),f2s(v0.z),f2s(v0.w),
                      f2s(v1.x),f2s(v1.y),f2s(v1.z),f2s(v1.w)};
  }
#pragma unroll
  for (int ks = 4; ks < 12; ++ks) {
    float4 v0 = *(const float4*)(zsrc + (ks-4)*32 + qd*8);
    float4 v1 = *(const float4*)(zsrc + (ks-4)*32 + qd*8 + 4);
    af[ks] = (short8){f2s(v0.x),f2s(v0.y),f2s(v0.z),f2s(v0.w),
                      f2s(v1.x),f2s(v1.y),f2s(v1.z),f2s(v1.w)};
  }

  const short* Wb = (const short*)WTin + ln*384 + qd*8;
  f32x4 acc[8];
#pragma unroll
  for (int ct = 0; ct < 8; ++ct) acc[ct] = (f32x4){0,0,0,0};
#pragma unroll
  for (int ks = 0; ks < 12; ++ks)
#pragma unroll
    for (int ct = 0; ct < 8; ++ct)
      acc[ct] = __builtin_amdgcn_mfma_f32_16x16x32_bf16(af[ks],
                  *(const short8*)(Wb + ct*16*384 + ks*32), acc[ct], 0,0,0);

#pragma unroll
  for (int ct = 0; ct < 8; ++ct) {
    int col = ct*16 + ln;
    float bias = b[col];
#pragma unroll
    for (int reg = 0; reg < 4; ++reg) {
      int crow = row0w + qd*4 + reg;
      float v = fmaxf(acc[ct][reg] + bias, 0.f);
      size_t o = (size_t)crow*128 + col;
      h[o] = v;
      h_bf[o] = f2bf(v);
    }
  }
}

// ============ MFMA edge GEMM v3: wave = 32 rows x 64 cols; A loaded upfront,
// VGPR cap raised via __launch_bounds__(256,2) so prefetch stays live.
// m residual for MODE>=1 served from an LDS echo of the wave's own A-frags.
// MODE 0: out = bf16(relu(hs@W1 + hd@W2 + T0(d) + b))         (KD=256)
// MODE 1: out = bf16(m + relu([hs|hd|m]@W + b))               (KD=384)
// MODE 2: MODE1 value v, NO m store; atomicAdd(fout[row], sum_col v*Wf)
template<int KD, int MODE>
__global__ __launch_bounds__(256, 2) void k_egemm(
    const int* __restrict__ src, const int* __restrict__ dst,
    const __hip_bfloat16* __restrict__ h_bf,
    const __hip_bfloat16* __restrict__ m_in,
    const float* __restrict__ dist, const float* __restrict__ T0,
    const __hip_bfloat16* __restrict__ WT, const float* __restrict__ b,
    __hip_bfloat16* __restrict__ out,
    const float* __restrict__ Wf, float* __restrict__ fout) {
  constexpr int MECHN = (MODE >= 1) ? 4*32*132 : 4;
  __shared__ short mech[MECHN];     // per-wave m-tile echo, pitch 132 shorts
  const int tid = threadIdx.x;
  const int w = tid >> 6, lane = tid & 63, ln = lane & 15, qd = lane >> 4;
  const int cg = w & 1, rh = w >> 1;
  const int row0 = blockIdx.x * 64 + rh * 32;
  constexpr int NSEG = KD / 32;

  const int r_a = row0 + ln, r_b = row0 + 16 + ln;

  // ---- phase 1: issue ALL A-fragment loads (independent, stay in flight) ----
  short8 afA[NSEG], afB[NSEG];
  {
    const short* hsA = (const short*)h_bf + (size_t)src[r_a]*HID + qd*8;
    const short* hdA = (const short*)h_bf + (size_t)dst[r_a]*HID + qd*8;
    const short* hsB = (const short*)h_bf + (size_t)src[r_b]*HID + qd*8;
    const short* hdB = (const short*)h_bf + (size_t)dst[r_b]*HID + qd*8;
#pragma unroll
    for (int k2 = 0; k2 < 4; ++k2) {
      afA[k2]   = *(const short8*)(hsA + k2*32);
      afB[k2]   = *(const short8*)(hsB + k2*32);
      afA[4+k2] = *(const short8*)(hdA + k2*32);
      afB[4+k2] = *(const short8*)(hdB + k2*32);
    }
    if constexpr (MODE >= 1) {
      const short* thA = (const short*)m_in + (size_t)r_a*HID + qd*8;
      const short* thB = (const short*)m_in + (size_t)r_b*HID + qd*8;
#pragma unroll
      for (int k2 = 0; k2 < 4; ++k2) {
        afA[8+k2] = *(const short8*)(thA + k2*32);
        afB[8+k2] = *(const short8*)(thB + k2*32);
      }
      // echo m tile to LDS for the epilogue residual (same wave, no barrier)
#pragma unroll
      for (int k2 = 0; k2 < 4; ++k2) {
        *(short8*)&mech[(w*32 + ln     )*132 + k2*32 + qd*8] = afA[8+k2];
        *(short8*)&mech[(w*32 + 16 + ln)*132 + k2*32 + qd*8] = afB[8+k2];
      }
    }
  }

  // ---- phase 2: B loop (L2-resident weights) + MFMAs ----
  f32x4 acc0[4], acc1[4];
#pragma unroll
  for (int ct = 0; ct < 4; ++ct) { acc0[ct] = (f32x4){0,0,0,0}; acc1[ct] = (f32x4){0,0,0,0}; }

#pragma unroll
  for (int ks = 0; ks < NSEG; ++ks) {
#pragma unroll
    for (int ct = 0; ct < 4; ++ct) {
      const short* bbp = (const short*)WT + (size_t)(cg*64 + ct*16 + ln)*KD + qd*8 + ks*32;
      short8 bb = *(const short8*)bbp;
      acc0[ct] = __builtin_amdgcn_mfma_f32_16x16x32_bf16(afA[ks], bb, acc0[ct], 0,0,0);
      acc1[ct] = __builtin_amdgcn_mfma_f32_16x16x32_bf16(afB[ks], bb, acc1[ct], 0,0,0);
    }
  }

  // ---- epilogue ----
  float bias4[4], wf4[4];
#pragma unroll
  for (int ct = 0; ct < 4; ++ct) bias4[ct] = b[cg*64 + ct*16 + ln];
  if constexpr (MODE == 2) {
#pragma unroll
    for (int ct = 0; ct < 4; ++ct) wf4[ct] = Wf[cg*64 + ct*16 + ln];
  }

#pragma unroll
  for (int mt = 0; mt < 2; ++mt) {
    const f32x4* acc = mt ? acc1 : acc0;
#pragma unroll
    for (int reg = 0; reg < 4; ++reg) {
      int row = row0 + mt*16 + qd*4 + reg;
      float dr = 0.f;
      if constexpr (MODE == 0) dr = dist[row];
      float fp = 0.f;
#pragma unroll
      for (int ct = 0; ct < 4; ++ct) {
        int col = cg*64 + ct*16 + ln;
        float v;
        if constexpr (MODE == 0) {
          v = fmaxf(acc[ct][reg] + bias4[ct] + tlook(T0, dr, col), 0.f);
        } else {
          float res = s2f(mech[(w*32 + mt*16 + qd*4 + reg)*132 + col]);
          v = fmaxf(acc[ct][reg] + bias4[ct], 0.f) + res;
        }
        if constexpr (MODE != 2) out[(size_t)row*HID + col] = f2bf(v);
        if constexpr (MODE == 2) fp = fmaf(v, wf4[ct], fp);
      }
      if constexpr (MODE == 2) {
        fp += __shfl_xor(fp, 1, 64);
        fp += __shfl_xor(fp, 2, 64);
        fp += __shfl_xor(fp, 4, 64);
        fp += __shfl_xor(fp, 8, 64);
        if (ln == 0) atomicAdd(&fout[row], fp);   // fbuf pre-init to b_force
      }
    }
  }
}

// ===== fused msg+segsum, NPART partial blocks per crystal -> bf16 aggP slices
// msg = relu(m@Wm+bm) * gate(d).  256 thr = 4 waves; one tile live at a time
// (no register hoarding -> no scratch spill).  10 tiles of 16 edges per block.
__global__ __launch_bounds__(256) void k_msgagg(
    const __hip_bfloat16* __restrict__ m, const float* __restrict__ dist,
    const __hip_bfloat16* __restrict__ WmT, const float* __restrict__ bm,
    const float* __restrict__ Tg, const int* __restrict__ dst,
    __hip_bfloat16* __restrict__ aggP) {
  __shared__ float agg[64 * 132];
  const int tid = threadIdx.x;
  const int c = blockIdx.x & 255, pq = blockIdx.x >> 8;
  const int w = tid >> 6, lane = tid & 63, ln = lane & 15, qd = lane >> 4;

  for (int i = tid; i < 64*132; i += 256) agg[i] = 0.f;
  float bias8[8];
#pragma unroll
  for (int ct = 0; ct < 8; ++ct) bias8[ct] = bm[ct*16 + ln];
  __syncthreads();

  for (int s = w; s < 10; s += 4) {
    int e0 = c * 1280 + pq * 160 + s * 16;
    const short* pm = (const short*)m + (size_t)(e0 + ln)*HID + qd*8;
    short8 am[4];
#pragma unroll
    for (int ks = 0; ks < 4; ++ks) am[ks] = *(const short8*)(pm + ks*32);
    int d4[4], i04[4]; float fr4[4]; bool in4[4];
#pragma unroll
    for (int reg = 0; reg < 4; ++reg) {
      d4[reg] = dst[e0 + qd*4 + reg] & 63;
      float dd = dist[e0 + qd*4 + reg];
      in4[reg] = dd < CUT_F;
      float x = fminf(dd, CUT_F) * ((float)(DQ - 1) / CUT_F);
      i04[reg] = (int)x;
      fr4[reg] = x - (float)i04[reg];
    }
    f32x4 accM[8];
#pragma unroll
    for (int ct = 0; ct < 8; ++ct) accM[ct] = (f32x4){0,0,0,0};
#pragma unroll
    for (int ct = 0; ct < 8; ++ct) {
      const short* bmp = (const short*)WmT + (ct*16 + ln)*128 + qd*8;
#pragma unroll
      for (int ks = 0; ks < 4; ++ks)
        accM[ct] = __builtin_amdgcn_mfma_f32_16x16x32_bf16(am[ks],
                     *(const short8*)(bmp + ks*32), accM[ct], 0,0,0);
    }
#pragma unroll
    for (int ct = 0; ct < 8; ++ct) {
      int col = ct*16 + ln;
#pragma unroll
      for (int reg = 0; reg < 4; ++reg) {
        if (in4[reg]) {
          const float* tp = Tg + (size_t)i04[reg]*128 + col;
          float g = fmaf(fr4[reg], tp[128] - tp[0], tp[0]);
          float v = fmaxf(accM[ct][reg] + bias8[ct], 0.f) * g;
          if (v != 0.f) atomicAdd(&agg[d4[reg]*132 + col], v);
        }
      }
    }
  }
  __syncthreads();
  __hip_bfloat16* outp = aggP + ((size_t)pq * NATOMS + c * 64) * HID;
  for (int i = tid; i < 64*128; i += 256) {
    int a = i >> 7, col = i & 127;
    outp[a*HID + col] = f2bf(agg[a*132 + col]);
  }
}

// ============ MFMA fc (K=128): Y = [res +] relu(A@W + b)
__global__ __launch_bounds__(256) void k_fcm(
    const __hip_bfloat16* __restrict__ A,       // nslice==1
    const __hip_bfloat16* __restrict__ slices,  // nslice==NPART
    int nslice,
    const __hip_bfloat16* __restrict__ WT, const float* __restrict__ b,
    const float* __restrict__ resIn,            // nullable
    float* __restrict__ Yf,                     // nullable
    __hip_bfloat16* __restrict__ Ybf) {         // nullable
  const int tid = threadIdx.x;
  const int w = tid >> 6, lane = tid & 63, ln = lane & 15, qd = lane >> 4;
  const int row0w = blockIdx.x * 64 + w * 16;
  const int arow = row0w + ln;

  short8 af[4];
  if (nslice == 1) {
    const short* pa = (const short*)A + (size_t)arow*128 + qd*8;
#pragma unroll
    for (int ks = 0; ks < 4; ++ks) af[ks] = *(const short8*)(pa + ks*32);
  } else {
#pragma unroll
    for (int ks = 0; ks < 4; ++ks) {
      float s[8] = {0,0,0,0,0,0,0,0};
#pragma unroll
      for (int p = 0; p < NPART; ++p) {
        short8 v = *(const short8*)((const short*)slices +
                     (size_t)p*NATOMS*128 + (size_t)arow*128 + qd*8 + ks*32);
#pragma unroll
        for (int u = 0; u < 8; ++u) s[u] += s2f(v[u]);
      }
      af[ks] = (short8){f2s(s[0]),f2s(s[1]),f2s(s[2]),f2s(s[3]),
                        f2s(s[4]),f2s(s[5]),f2s(s[6]),f2s(s[7])};
    }
  }

  const short* Wb = (const short*)WT + ln*128 + qd*8;
  f32x4 acc[8];
#pragma unroll
  for (int ct = 0; ct < 8; ++ct) acc[ct] = (f32x4){0,0,0,0};
#pragma unroll
  for (int ct = 0; ct < 8; ++ct)
#pragma unroll
    for (int ks = 0; ks < 4; ++ks)
      acc[ct] = __builtin_amdgcn_mfma_f32_16x16x32_bf16(af[ks],
                  *(const short8*)(Wb + ct*16*128 + ks*32), acc[ct], 0,0,0);

#pragma unroll
  for (int ct = 0; ct < 8; ++ct) {
    int col = ct*16 + ln;
    float bias = b[col];
#pragma unroll
    for (int reg = 0; reg < 4; ++reg) {
      int crow = row0w + qd*4 + reg;
      size_t o = (size_t)crow*128 + col;
      float v = fmaxf(acc[ct][reg] + bias, 0.f);
      if (resIn) v += resIn[o];
      if (Yf)  Yf[o] = v;
      if (Ybf) Ybf[o] = f2bf(v);
    }
  }
}

// ----------------------------------- pred_cart = segsum(f*unit) per crystal
__global__ void k_pcart(const float* __restrict__ f, const float* __restrict__ unit,
                        const int* __restrict__ dst, float* __restrict__ out) {
  __shared__ float acc[AATOMS * 3];
  int c = blockIdx.x, tid = threadIdx.x;  // 256 threads
  if (tid < AATOMS*3) acc[tid] = 0.f;
  __syncthreads();
  for (int t = tid; t < 1280; t += 256) {
    int e = c*1280 + t;
    int d = dst[e] & 63;
    float fv = f[e];
    atomicAdd(&acc[d*3+0], fv * unit[e*3+0]);
    atomicAdd(&acc[d*3+1], fv * unit[e*3+1]);
    atomicAdd(&acc[d*3+2], fv * unit[e*3+2]);
  }
  __syncthreads();
  if (tid < AATOMS*3) out[c*AATOMS*3 + tid] = acc[tid];
}

// ----------------------------------------- final fc3: (128 -> 2) per atom row
__global__ void k_fc3(const float* __restrict__ a2, const float* __restrict__ W,
                      const float* __restrict__ b, float* __restrict__ out) {
  int lane = threadIdx.x & 63;
  int wave = threadIdx.x >> 6;
  int row = blockIdx.x * 4 + wave;
  float x0 = a2[(size_t)row*HID + lane], x1 = a2[(size_t)row*HID + 64 + lane];
  float p0 = x0 * W[lane*2+0] + x1 * W[(64+lane)*2+0];
  float p1 = x0 * W[lane*2+1] + x1 * W[(64+lane)*2+1];
#pragma unroll
  for (int off = 32; off > 0; off >>= 1) {
    p0 += __shfl_down(p0, off, 64);
    p1 += __shfl_down(p1, off, 64);
  }
  if (lane == 0) {
    out[row*2+0] = p0 + b[0];
    out[row*2+1] = p1 + b[1];
  }
}

extern "C" void kernel_launch(void* const* d_in, const int* in_sizes, int n_in,
                              void* d_out, int out_size, void* d_ws, size_t ws_size,
                              hipStream_t stream) {
  const float* z        = (const float*)d_in[0];
  const float* frac     = (const float*)d_in[1];
  const float* lengths  = (const float*)d_in[2];
  const float* angles   = (const float*)d_in[3];
  const int*   atype    = (const int*)  d_in[4];
  const int*   src      = (const int*)  d_in[5];
  const int*   dst      = (const int*)  d_in[6];
  const float* emb      = (const float*)d_in[7];
  const float* W_in     = (const float*)d_in[8];
  const float* b_in     = (const float*)d_in[9];
  const float* W_edge   = (const float*)d_in[10];
  const float* b_edge   = (const float*)d_in[11];
  const float* Wb_rbf   = (const float*)d_in[12];
  const float* Wb_msg   = (const float*)d_in[13];
  const float* bb_msg   = (const float*)d_in[14];
  const float* Wb_atom  = (const float*)d_in[15];
  const float* bb_atom  = (const float*)d_in[16];
  const float* Wb_upd   = (const float*)d_in[17];
  const float* bb_upd   = (const float*)d_in[18];
  const float* W_force  = (const float*)d_in[19];
  const float* b_force  = (const float*)d_in[20];
  const float* W_fc1    = (const float*)d_in[21];
  const float* b_fc1    = (const float*)d_in[22];
  const float* W_fc2    = (const float*)d_in[23];
  const float* b_fc2    = (const float*)d_in[24];
  const float* W_fc3    = (const float*)d_in[25];
  const float* b_fc3    = (const float*)d_in[26];

  // ---- workspace layout (~170 MB) ----
  char* p = (char*)d_ws;
  float* cart = (float*)p;            p += (size_t)NATOMS*3*4;
  float* unit = (float*)p;            p += (size_t)NEDGE*3*4;       // 3.9 MB
  float* dist = (float*)p;            p += (size_t)NEDGE*4;         // 1.3 MB
  float* h    = (float*)p;            p += (size_t)NATOMS*HID*4;    // 8.4 MB
  float* a2   = (float*)p;            p += (size_t)NATOMS*HID*4;    // 8.4 MB
  float* fbuf = (float*)p;            p += (size_t)NEDGE*4;         // 1.3 MB
  float* T    = (float*)p;            p += (size_t)4*DQ*128*4;      // 8.4 MB
  __hip_bfloat16* h_bf = (__hip_bfloat16*)p; p += (size_t)NATOMS*HID*2;
  __hip_bfloat16* a1bf = (__hip_bfloat16*)p; p += (size_t)NATOMS*HID*2;
  __hip_bfloat16* aggP = (__hip_bfloat16*)p; p += (size_t)NPART*NATOMS*HID*2; // 33.6 MB
  __hip_bfloat16* m    = (__hip_bfloat16*)p; p += (size_t)NEDGE*HID*2;        // 83.9 MB
  __hip_bfloat16* WT   = (__hip_bfloat16*)p; p += (size_t)360448*2;

  __hip_bfloat16* WT_in   = WT;
  __hip_bfloat16* WT_edge = WT + 49152;
  __hip_bfloat16* WT_upd  = WT + 81920;
  __hip_bfloat16* WT_msg  = WT + 229376;
  __hip_bfloat16* WT_atom = WT + 278528;
  __hip_bfloat16* WT_fc1  = WT + 327680;
  __hip_bfloat16* WT_fc2  = WT + 344064;

  float* out_cart = (float*)d_out;
  float* out_at   = out_cart + NATOMS*3;

  k_wcast<<<1408, 256, 0, stream>>>(W_in, W_edge, Wb_upd, Wb_msg, Wb_atom,
                                    W_fc1, W_fc2, WT);
  k_tab<<<DQ, 128, 0, stream>>>(W_edge, Wb_rbf, T);
  k_cart<<<NATOMS/256, 256, 0, stream>>>(frac, lengths, angles, cart);
  k_edge<<<NEDGE/256, 256, 0, stream>>>(cart, src, dst, unit, dist, b_force, fbuf);
  k_hm<<<NATOMS/64, 256, 0, stream>>>(atype, z, emb, WT_in, b_in, h, h_bf);
  k_egemm<256,0><<<NEDGE/64, 256, 0, stream>>>(src, dst, h_bf, nullptr, dist, T,
                                               WT_edge, b_edge, m, nullptr, nullptr);
  for (int i = 0; i < NBLK; ++i) {
    k_msgagg<<<NCRYST*NPART, 256, 0, stream>>>(m, dist, WT_msg + i*16384,
                                               bb_msg + i*HID, T + (size_t)(1+i)*DQ*128,
                                               dst, aggP);
    k_fcm<<<NATOMS/64, 256, 0, stream>>>(nullptr, aggP, NPART, WT_atom + i*16384,
                                         bb_atom + i*HID, h, h, h_bf);
    if (i < NBLK-1) {
      k_egemm<384,1><<<NEDGE/64, 256, 0, stream>>>(src, dst, h_bf, m, nullptr, nullptr,
                                                   WT_upd + i*49152, bb_upd + i*HID, m,
                                                   nullptr, nullptr);
    } else {
      k_egemm<384,2><<<NEDGE/64, 256, 0, stream>>>(src, dst, h_bf, m, nullptr, nullptr,
                                                   WT_upd + i*49152, bb_upd + i*HID,
                                                   nullptr, W_force, fbuf);
    }
  }
  k_pcart<<<NCRYST, 256, 0, stream>>>(fbuf, unit, dst, out_cart);
  k_fcm<<<NATOMS/64, 256, 0, stream>>>(h_bf, nullptr, 1, WT_fc1, b_fc1,
                                       nullptr, nullptr, a1bf);
  k_fcm<<<NATOMS/64, 256, 0, stream>>>(a1bf, nullptr, 1, WT_fc2, b_fc2,
                                       nullptr, a2, nullptr);
  k_fc3<<<NATOMS/4, 256, 0, stream>>>(a2, W_fc3, b_fc3, out_at);
}